// Round 4
// baseline (2116.766 us; speedup 1.0000x reference)
//
#include <hip/hip_runtime.h>
#include <hip/hip_bf16.h>

// GCN GraphConv (norm='both', mult-first): out = relu( D_in^-1/2 * A * D_out^-1/2 * (X W) + b )
// N=100000 nodes, E=3200000 edges, IN=128, OUT=64, fp32 in/out.
//
// R15 pipeline (de-fused, each stage minimal):
//  1. prep: per edge: ONE global rtn-atomic routes it into its 128-node dst bucket
//     (payload (dst&127)<<17 | src), plus deg_out atomic into 8 L2-spread replicas.
//     No LDS sort, no scans (agg sorts locally anyway).
//  2. rsq: sum 8 replicas -> rsq_out = rsqrt(max(deg_out,1)).
//  3. gemm: 64-row tile, 2 rows x 4 cols per thread (3 B LDS / MAC), XOR-swizzled
//     x tile, epilogue scales by rsq_out -> bf16 sxw (R13-verified numerics).
//  4. agg: per-bucket in-LDS counting sort by dst-local (R14-verified), then
//     8-lane-group-per-node VGPR gather: zero shuffles, 4 edges in flight,
//     pure unpack+add (sxw pre-scaled), fused rsqrt(deg_in)+bias+relu epilogue.

constexpr int N_NODES = 100000;
constexpr int N_EDGES = 3200000;
constexpr int IN_F    = 128;
constexpr int OUT_F   = 64;
constexpr int BKT     = 128;                         // nodes per dst bucket
constexpr int NB2     = (N_NODES + BKT - 1) / BKT;   // 782
constexpr int CAPB2   = 5120;        // mean 4096, sd ~64 -> 16 sigma headroom
constexpr int NREP    = 8;           // deg_out replicas

static __device__ __forceinline__ unsigned short f2bf(float f) {
    unsigned u = __float_as_uint(f);
    u += 0x7fffu + ((u >> 16) & 1u);
    return (unsigned short)(u >> 16);
}

// ---- Kernel 1: edge routing + deg histogram, pure global atomics ----
__global__ __launch_bounds__(256) void prep_kernel(
        const int* __restrict__ src, const int* __restrict__ dst,
        int* __restrict__ bucket_cnt, unsigned* __restrict__ pairs,
        int* __restrict__ deg8) {
    const int t = blockIdx.x * 256 + threadIdx.x;    // 0..799999 (4 edges each)
    int* mydeg = deg8 + (size_t)(blockIdx.x & (NREP - 1)) * N_NODES;
    int4 s4 = ((const int4*)src)[t];
    int4 d4 = ((const int4*)dst)[t];
    int ss[4] = {s4.x, s4.y, s4.z, s4.w};
    int dd[4] = {d4.x, d4.y, d4.z, d4.w};
    #pragma unroll
    for (int j = 0; j < 4; ++j) {
        int bk = dd[j] >> 7;
        unsigned pk = ((unsigned)(dd[j] & 127) << 17) | (unsigned)ss[j];
        int pos = atomicAdd(&bucket_cnt[bk], 1);
        if (pos < CAPB2)                             // 16-sigma safety
            pairs[(long)bk * CAPB2 + pos] = pk;
        atomicAdd(&mydeg[ss[j]], 1);
    }
}

// ---- Kernel 2: reduce replicas -> rsq_out ----
__global__ __launch_bounds__(256) void rsq_kernel(
        const int* __restrict__ deg8, float* __restrict__ rsq_out) {
    const int node = blockIdx.x * 256 + threadIdx.x;
    if (node < N_NODES) {
        int d = 0;
        #pragma unroll
        for (int r = 0; r < NREP; ++r) d += deg8[(size_t)r * N_NODES + node];
        rsq_out[node] = rsqrtf((float)(d < 1 ? 1 : d));
    }
}

// ---- Kernel 3: gemm, 64-row tile, 2x4 per thread, scaled bf16 output ----
__global__ __launch_bounds__(512) void gemm_kernel(
        const float* __restrict__ x, const float* __restrict__ W,
        const float* __restrict__ rsq_out, __hip_bfloat16* __restrict__ sxw) {
    __shared__ float Wl[IN_F * OUT_F];     // 32768 B  [128][64]
    __shared__ float xl[64 * IN_F];        // 32768 B  [64][128], quads XOR-swizzled
    const int tid  = threadIdx.x;
    const int base = blockIdx.x * 64;

    float4* Wl4 = (float4*)Wl;
    #pragma unroll
    for (int k = 0; k < 4; ++k)
        Wl4[tid + k * 512] = ((const float4*)W)[tid + k * 512];

    float4* xl4 = (float4*)xl;
    #pragma unroll
    for (int k = 0; k < 4; ++k) {
        int i = tid + k * 512;             // 2048 quads = 64 rows x 32
        int row = i >> 5, q = i & 31;
        int grow = base + row;
        float4 v = ((const float4*)x)[(long)(grow < N_NODES ? grow : N_NODES - 1) * 32 + q];
        xl4[row * 32 + ((q + row) & 31)] = v;   // swizzle: row-stagger banks
    }
    __syncthreads();

    const int c4 = tid & 15;               // col quad 0..15
    const int rp = tid >> 4;               // 0..31 -> rows 2rp, 2rp+1
    const int r0 = rp * 2, r1 = r0 + 1;
    float4 a0 = {0, 0, 0, 0}, a1 = {0, 0, 0, 0};
    #pragma unroll
    for (int k4 = 0; k4 < IN_F / 4; ++k4) {
        float4 xv0 = xl4[r0 * 32 + ((k4 + r0) & 31)];
        float4 xv1 = xl4[r1 * 32 + ((k4 + r1) & 31)];
        float4 w0 = Wl4[(k4 * 4 + 0) * 16 + c4];   // 256B span, 2-way -> free
        float4 w1 = Wl4[(k4 * 4 + 1) * 16 + c4];
        float4 w2 = Wl4[(k4 * 4 + 2) * 16 + c4];
        float4 w3 = Wl4[(k4 * 4 + 3) * 16 + c4];
        a0.x += xv0.x * w0.x + xv0.y * w1.x + xv0.z * w2.x + xv0.w * w3.x;
        a0.y += xv0.x * w0.y + xv0.y * w1.y + xv0.z * w2.y + xv0.w * w3.y;
        a0.z += xv0.x * w0.z + xv0.y * w1.z + xv0.z * w2.z + xv0.w * w3.z;
        a0.w += xv0.x * w0.w + xv0.y * w1.w + xv0.z * w2.w + xv0.w * w3.w;
        a1.x += xv1.x * w0.x + xv1.y * w1.x + xv1.z * w2.x + xv1.w * w3.x;
        a1.y += xv1.x * w0.y + xv1.y * w1.y + xv1.z * w2.y + xv1.w * w3.y;
        a1.z += xv1.x * w0.z + xv1.y * w1.z + xv1.z * w2.z + xv1.w * w3.z;
        a1.w += xv1.x * w0.w + xv1.y * w1.w + xv1.z * w2.w + xv1.w * w3.w;
    }
    const int g0 = base + r0, g1 = base + r1;
    if (g0 < N_NODES) {
        float rs = rsq_out[g0];
        ushort4 o;
        o.x = f2bf(a0.x * rs); o.y = f2bf(a0.y * rs);
        o.z = f2bf(a0.z * rs); o.w = f2bf(a0.w * rs);
        ((ushort4*)sxw)[(long)g0 * 16 + c4] = o;
    }
    if (g1 < N_NODES) {
        float rs = rsq_out[g1];
        ushort4 o;
        o.x = f2bf(a1.x * rs); o.y = f2bf(a1.y * rs);
        o.z = f2bf(a1.z * rs); o.w = f2bf(a1.w * rs);
        ((ushort4*)sxw)[(long)g1 * 16 + c4] = o;
    }
}

// ---- Kernel 4: per-bucket sort + group-per-node VGPR gather (no shuffles) ----
#define ACC8(u) {                                    \
    a0 += __uint_as_float((u).x << 16);              \
    a1 += __uint_as_float((u).x & 0xFFFF0000u);      \
    a2 += __uint_as_float((u).y << 16);              \
    a3 += __uint_as_float((u).y & 0xFFFF0000u);      \
    a4 += __uint_as_float((u).z << 16);              \
    a5 += __uint_as_float((u).z & 0xFFFF0000u);      \
    a6 += __uint_as_float((u).w << 16);              \
    a7 += __uint_as_float((u).w & 0xFFFF0000u);      \
}

__global__ __launch_bounds__(512) void agg_kernel(
        const unsigned* __restrict__ pairs, const int* __restrict__ bucket_cnt,
        const uint4* __restrict__ sxw4, const float* __restrict__ b,
        float* __restrict__ out) {
    __shared__ unsigned sorted[CAPB2];         // 20480 B (src ids, dl-sorted)
    __shared__ int hist[BKT];
    __shared__ int cur[BKT];
    __shared__ int begs[BKT + 1];
    __shared__ int wsum[8];
    const int tid  = threadIdx.x;
    const int bk   = blockIdx.x;
    const int lane = tid & 63;
    const int wid  = tid >> 6;

    if (tid < BKT) hist[tid] = 0;
    __syncthreads();

    const long base = (long)bk * CAPB2;
    const int  cnt  = min(bucket_cnt[bk], CAPB2);
    const int  n4   = cnt >> 2;
    const uint4* p4 = (const uint4*)(pairs + base);

    // load up to 12 edges/thread into registers, histogram dl (1 atomic/edge)
    unsigned ev[12];
    #pragma unroll
    for (int k = 0; k < 3; ++k) {
        const int i4 = tid + k * 512;
        if (i4 < n4) {
            uint4 q = p4[i4];
            ev[k * 4 + 0] = q.x; ev[k * 4 + 1] = q.y;
            ev[k * 4 + 2] = q.z; ev[k * 4 + 3] = q.w;
            atomicAdd(&hist[q.x >> 17], 1);
            atomicAdd(&hist[q.y >> 17], 1);
            atomicAdd(&hist[q.z >> 17], 1);
            atomicAdd(&hist[q.w >> 17], 1);
        } else {
            ev[k * 4 + 0] = 0xFFFFFFFFu; ev[k * 4 + 1] = 0xFFFFFFFFu;
            ev[k * 4 + 2] = 0xFFFFFFFFu; ev[k * 4 + 3] = 0xFFFFFFFFu;
        }
    }
    unsigned et = 0xFFFFFFFFu;                 // tail (cnt & 3 edges)
    if (tid < (cnt & 3)) {
        et = pairs[base + (n4 << 2) + tid];
        atomicAdd(&hist[et >> 17], 1);
    }
    __syncthreads();

    // exclusive scan of 128 bins (2 waves)
    {
        int v = (tid < BKT) ? hist[tid] : 0;
        int inc = v;
        #pragma unroll
        for (int off = 1; off < 64; off <<= 1) {
            int t = __shfl_up(inc, off);
            if (lane >= off) inc += t;
        }
        if (tid < BKT && lane == 63) wsum[wid] = inc;
        __syncthreads();
        if (tid < BKT) {
            int excl = inc - v + (wid ? wsum[0] : 0);
            begs[tid] = excl;
            cur[tid]  = excl;
        }
        if (tid == 0) begs[BKT] = cnt;
        __syncthreads();
    }

    // scatter src into dl-sorted LDS array (1 rtn-atomic/edge)
    #pragma unroll
    for (int k = 0; k < 12; ++k) {
        if (ev[k] != 0xFFFFFFFFu) {
            int dl = (int)(ev[k] >> 17);
            int p  = atomicAdd(&cur[dl], 1);
            sorted[p] = ev[k] & 0x1FFFFu;
        }
    }
    if (et != 0xFFFFFFFFu) {
        int dl = (int)(et >> 17);
        int p  = atomicAdd(&cur[dl], 1);
        sorted[p] = et & 0x1FFFFu;
    }
    __syncthreads();

    // gather: 8-lane group per node, 2 nodes per group, zero shuffles
    const int grp = tid >> 3;                  // 0..63
    const int c   = tid & 7;                   // uint4 col 0..7
    const float4 b0 = ((const float4*)b)[c * 2];
    const float4 b1 = ((const float4*)b)[c * 2 + 1];
    const int node0 = bk * BKT;

    #pragma unroll
    for (int half = 0; half < 2; ++half) {
        const int n    = grp + half * 64;
        const int node = node0 + n;
        if (node < N_NODES) {
            const int jb = begs[n], je = begs[n + 1];
            float a0 = 0, a1 = 0, a2 = 0, a3 = 0, a4 = 0, a5 = 0, a6 = 0, a7 = 0;
            int j = jb;
            for (; j + 4 <= je; j += 4) {      // 4 edges in flight
                int s0 = (int)sorted[j];
                int s1 = (int)sorted[j + 1];
                int s2 = (int)sorted[j + 2];
                int s3 = (int)sorted[j + 3];
                uint4 u0 = sxw4[(unsigned)s0 * 8u + c];
                uint4 u1 = sxw4[(unsigned)s1 * 8u + c];
                uint4 u2 = sxw4[(unsigned)s2 * 8u + c];
                uint4 u3 = sxw4[(unsigned)s3 * 8u + c];
                ACC8(u0) ACC8(u1) ACC8(u2) ACC8(u3)
            }
            for (; j < je; ++j) {
                int s = (int)sorted[j];
                uint4 u = sxw4[(unsigned)s * 8u + c];
                ACC8(u)
            }
            int dg = je - jb;
            float s = rsqrtf((float)(dg < 1 ? 1 : dg));
            float4 o0, o1;
            o0.x = fmaxf(fmaf(a0, s, b0.x), 0.0f);
            o0.y = fmaxf(fmaf(a1, s, b0.y), 0.0f);
            o0.z = fmaxf(fmaf(a2, s, b0.z), 0.0f);
            o0.w = fmaxf(fmaf(a3, s, b0.w), 0.0f);
            o1.x = fmaxf(fmaf(a4, s, b1.x), 0.0f);
            o1.y = fmaxf(fmaf(a5, s, b1.y), 0.0f);
            o1.z = fmaxf(fmaf(a6, s, b1.z), 0.0f);
            o1.w = fmaxf(fmaf(a7, s, b1.w), 0.0f);
            float4* orow = (float4*)(out + (long)node * OUT_F);
            orow[c * 2]     = o0;
            orow[c * 2 + 1] = o1;
        }
    }
}

extern "C" void kernel_launch(void* const* d_in, const int* in_sizes, int n_in,
                              void* d_out, int out_size, void* d_ws, size_t ws_size,
                              hipStream_t stream) {
    const float* in_feat = (const float*)d_in[0];
    const int*   src     = (const int*)d_in[1];
    const int*   dst     = (const int*)d_in[2];
    const float* W       = (const float*)d_in[3];
    const float* b       = (const float*)d_in[4];
    float*       out     = (float*)d_out;

    // ws: sxw bf16 [N*64] (12.8MB) | deg8 [8*N] (3.2MB) | bucket_cnt [784]
    //   | rsq_out [N] (400KB) | pairs [782*5120 u32] (16.0MB)
    __hip_bfloat16* sxw        = (__hip_bfloat16*)d_ws;
    int*            deg8       = (int*)(sxw + (size_t)N_NODES * OUT_F);
    int*            bucket_cnt = deg8 + (size_t)NREP * N_NODES;
    float*          rsq_out    = (float*)(bucket_cnt + 784);
    unsigned*       pairs      = (unsigned*)(rsq_out + N_NODES);

    // zero deg replicas + bucket_cnt (contiguous)
    hipMemsetAsync(deg8, 0, ((size_t)NREP * N_NODES + 784) * sizeof(int), stream);

    prep_kernel<<<N_EDGES / 4 / 256, 256, 0, stream>>>(src, dst, bucket_cnt,
                                                       pairs, deg8);

    rsq_kernel<<<(N_NODES + 255) / 256, 256, 0, stream>>>(deg8, rsq_out);

    gemm_kernel<<<(N_NODES + 63) / 64, 512, 0, stream>>>(in_feat, W, rsq_out, sxw);

    agg_kernel<<<NB2, 512, 0, stream>>>(pairs, bucket_cnt,
                                        (const uint4*)sxw, b, out);
}

// Round 5
// 370.567 us; speedup vs baseline: 5.7122x; 5.7122x over previous
//
#include <hip/hip_runtime.h>
#include <hip/hip_bf16.h>

// GCN GraphConv (norm='both', mult-first): out = relu( D_in^-1/2 * A * D_out^-1/2 * (X W) + b )
// N=100000 nodes, E=3200000 edges, IN=128, OUT=64, fp32 in/out.
//
// R16 = verified 260us baseline pipeline with two surgical cuts:
//  1. partition: dst counting sort UNCHANGED, but src-byte sort DELETED;
//     deg_out via fire-and-forget global atomics into 4 replicas (per-node
//     lines, no hot counters), overlapped with the LDS sort phases.
//  2. rsq: fold replicas -> rsq_out = rsqrt(max(deg_out,1))   (~3us, replaces count)
//  3. mega: csr path BYTE-IDENTICAL to baseline; gemm path uses R14's verified
//     1-row x 4-col float4 inner loop (5 LDS instr / 16 FMA), scale by rsq_out.
//  4. gather: BYTE-IDENTICAL to the 260us baseline.

constexpr int N_NODES = 100000;
constexpr int N_EDGES = 3200000;
constexpr int IN_F    = 128;
constexpr int OUT_F   = 64;
constexpr int BUCKET_NODES = 256;
constexpr int NB   = (N_NODES + BUCKET_NODES - 1) / BUCKET_NODES;  // 391
constexpr int CAPB = 10240;          // bucket capacity; mean 8184, sd~90 -> 22 sigma
constexpr int C_CHUNK  = 4096;
constexpr int C_BLOCKS = (N_EDGES + C_CHUNK - 1) / C_CHUNK;        // 782 (last cn=1024, %4==0)
constexpr int G_TILE   = 32;         // gemm rows per block-iteration
constexpr int G_BLOCKS = 1024;
constexpr int G_GROUPS = N_NODES / G_TILE;                         // 3125
constexpr int XLS      = 136;        // padded x-tile row stride (floats)
constexpr int NREP     = 4;          // deg_out replicas

static __device__ __forceinline__ unsigned short f2bf(float f) {
    unsigned u = __float_as_uint(f);
    u += 0x7fffu + ((u >> 16) & 1u);
    return (unsigned short)(u >> 16);
}

// ---- Kernel 1: dst partition (single counting sort) + deg_out atomics ----
__global__ __launch_bounds__(512) void partition_kernel(
        const int* __restrict__ src, const int* __restrict__ dst,
        int* __restrict__ bucket_cnt, unsigned* __restrict__ pairs,
        int* __restrict__ deg4) {
    __shared__ int l_cnt[NB], l_base[NB], l_pos[NB], g_base[NB];
    __shared__ int wsum_s[8];
    __shared__ unsigned buf[C_CHUNK];             // 16 KB (dst-sorted pairs)
    __shared__ unsigned short bkt_of[C_CHUNK];    // 8 KB
    const int tid  = threadIdx.x;
    const int lane = tid & 63;
    const int wid  = tid >> 6;                    // 0..7
    const long e0 = (long)blockIdx.x * C_CHUNK;
    const int  cn = (int)min((long)C_CHUNK, (long)N_EDGES - e0);
    const int  cn4 = cn >> 2;                     // cn is always a multiple of 4
    int* mydeg = deg4 + (size_t)(blockIdx.x & (NREP - 1)) * N_NODES;

    for (int i = tid; i < NB; i += 512) l_cnt[i] = 0;
    __syncthreads();

    // load edges as int4 (4 edges per load), count dst buckets, deg atomics
    unsigned r_pk[8];
    short    r_bk[8];
    const int4* d4p = (const int4*)(dst + e0);
    const int4* s4p = (const int4*)(src + e0);
    #pragma unroll
    for (int k = 0; k < 2; ++k) {
        int i4 = tid + k * 512;
        int rb = k * 4;
        if (i4 < cn4) {
            int4 d4 = d4p[i4];
            int4 s4 = s4p[i4];
            int dd[4] = {d4.x, d4.y, d4.z, d4.w};
            int ss[4] = {s4.x, s4.y, s4.z, s4.w};
            #pragma unroll
            for (int j = 0; j < 4; ++j) {
                int bk = dd[j] >> 8;
                r_bk[rb + j] = (short)bk;
                r_pk[rb + j] = ((unsigned)(dd[j] & 255) << 17) | (unsigned)ss[j];
                atomicAdd(&l_cnt[bk], 1);
                atomicAdd(&mydeg[ss[j]], 1);       // fire-and-forget, overlaps LDS
            }
        } else {
            #pragma unroll
            for (int j = 0; j < 4; ++j) r_bk[rb + j] = -1;
        }
    }
    __syncthreads();

    {   // scan: dst buckets -> l_base/l_pos, reserve global runs
        int v = (tid < NB) ? l_cnt[tid] : 0;
        int inc = v;
        #pragma unroll
        for (int off = 1; off < 64; off <<= 1) {
            int t = __shfl_up(inc, off);
            if (lane >= off) inc += t;
        }
        if (lane == 63) wsum_s[wid] = inc;
        __syncthreads();
        int woff = 0;
        #pragma unroll
        for (int w = 0; w < 8; ++w) if (w < wid) woff += wsum_s[w];
        int excl = woff + inc - v;
        if (tid < NB) {
            l_base[tid] = excl;
            l_pos[tid]  = excl;
            g_base[tid] = v ? atomicAdd(&bucket_cnt[tid], v) : 0;
        }
    }
    __syncthreads();

    // scatter into LDS (counting sort)
    #pragma unroll
    for (int k = 0; k < 8; ++k) {
        if (r_bk[k] >= 0) {
            int p = atomicAdd(&l_pos[(int)r_bk[k]], 1);
            buf[p] = r_pk[k];
            bkt_of[p] = (unsigned short)r_bk[k];
        }
    }
    __syncthreads();

    // coalesced flush
    for (int i = tid; i < cn; i += 512) {
        int bk = bkt_of[i];
        int gp = g_base[bk] + (i - l_base[bk]);
        if (gp < CAPB)                                 // 22-sigma safety
            pairs[(long)bk * CAPB + gp] = buf[i];
    }
}

// ---- Kernel 2: reduce replicas -> rsq_out ----
__global__ __launch_bounds__(256) void rsq_kernel(
        const int* __restrict__ deg4, float* __restrict__ rsq_out) {
    const int node = blockIdx.x * 256 + threadIdx.x;
    if (node < N_NODES) {
        int d = 0;
        #pragma unroll
        for (int r = 0; r < NREP; ++r) d += deg4[(size_t)r * N_NODES + node];
        rsq_out[node] = rsqrtf((float)(d < 1 ? 1 : d));
    }
}

// ---- Kernel 3 (mega): blocks < NB: csr counting sort; blocks >= NB: gemm ----
__global__ __launch_bounds__(512) void mega_kernel(
        unsigned* __restrict__ pairs, const int* __restrict__ bucket_cnt,
        int* __restrict__ row_beg, int* __restrict__ row_deg,
        const float* __restrict__ x, const float* __restrict__ W,
        const float* __restrict__ rsq_out, __hip_bfloat16* __restrict__ sxw) {
    alignas(16) __shared__ char smem[50176];       // union: csr 43KB | gemm 50176B
    const int tid = threadIdx.x;

    if (blockIdx.x < NB) {
        // ---------------- csr path (baseline-identical) ----------------
        unsigned* buf  = (unsigned*)smem;                    // 40960 B
        int*      hist = (int*)(smem + 40960);               // 1024 B
        int*      cur  = (int*)(smem + 40960 + 1024);        // 1024 B
        int*      wsum = (int*)(smem + 40960 + 2048);        // 16 B
        const int lane = tid & 63;
        const int wid  = tid >> 6;
        const int bk   = blockIdx.x;
        const long base = (long)bk * CAPB;
        const int cnt  = min(bucket_cnt[bk], CAPB);

        if (tid < 256) hist[tid] = 0;
        __syncthreads();

        const int c4 = cnt >> 2;
        const uint4* p4 = (const uint4*)(pairs + base);
        for (int i4 = tid; i4 < c4; i4 += 512) {
            uint4 e4 = p4[i4];
            ((uint4*)buf)[i4] = e4;                           // ds_write_b128
            atomicAdd(&hist[e4.x >> 17], 1);
            atomicAdd(&hist[e4.y >> 17], 1);
            atomicAdd(&hist[e4.z >> 17], 1);
            atomicAdd(&hist[e4.w >> 17], 1);
        }
        for (int i = (c4 << 2) + tid; i < cnt; i += 512) {
            unsigned e = pairs[base + i];
            buf[i] = e;
            atomicAdd(&hist[e >> 17], 1);
        }
        __syncthreads();

        int v = (tid < 256) ? hist[tid] : 0;
        int inc = v;
        #pragma unroll
        for (int off = 1; off < 64; off <<= 1) {
            int t = __shfl_up(inc, off);
            if (lane >= off) inc += t;
        }
        if (tid < 256 && lane == 63) wsum[wid] = inc;
        __syncthreads();
        if (tid < 256) {
            int woff = 0;
            #pragma unroll
            for (int w = 0; w < 4; ++w) if (w < wid) woff += wsum[w];
            int excl = woff + inc - v;
            cur[tid] = excl;
            const int node = bk * BUCKET_NODES + tid;
            if (node < N_NODES) {
                row_beg[node] = (int)(base + excl);
                row_deg[node] = v;
            }
        }
        __syncthreads();

        for (int i = tid; i < cnt; i += 512) {
            unsigned e = buf[i];
            int p = atomicAdd(&cur[e >> 17], 1);
            pairs[base + p] = e & 0x1FFFF;   // plain src, node-sorted
        }
    } else {
        // ---------------- gemm path (R14-verified inner loop) ----------------
        float* Wl = (float*)smem;                  // 32768 B  [128][64]
        float* xl = (float*)(smem + 32768);        // 17408 B  [32][136] padded
        for (int i = tid; i < IN_F * OUT_F; i += 512) Wl[i] = W[i];

        const int r  = tid >> 4;                   // 0..31 row
        const int c4 = tid & 15;                   // 0..15 col quad
        const float4* Wl4 = (const float4*)Wl;
        const int bid = blockIdx.x - NB;

        for (int g = bid; g < G_GROUPS; g += G_BLOCKS) {
            __syncthreads();                       // protect xl (and Wl on iter 0)
            const float4* xg = (const float4*)(x + (long)g * G_TILE * IN_F);
            #pragma unroll
            for (int k = 0; k < 2; ++k) {
                int i = tid + k * 512;
                int row = i >> 5, q = i & 31;
                ((float4*)xl)[row * (XLS / 4) + q] = xg[i];
            }
            __syncthreads();

            float4 a = {0.0f, 0.0f, 0.0f, 0.0f};
            const float4* xr4 = (const float4*)(xl + r * XLS);
            #pragma unroll
            for (int k4 = 0; k4 < IN_F / 4; ++k4) {
                float4 xv = xr4[k4];                       // conflict-free (pad)
                float4 w0 = Wl4[(k4 * 4 + 0) * 16 + c4];   // broadcast groups, free
                float4 w1 = Wl4[(k4 * 4 + 1) * 16 + c4];
                float4 w2 = Wl4[(k4 * 4 + 2) * 16 + c4];
                float4 w3 = Wl4[(k4 * 4 + 3) * 16 + c4];
                a.x += xv.x * w0.x + xv.y * w1.x + xv.z * w2.x + xv.w * w3.x;
                a.y += xv.x * w0.y + xv.y * w1.y + xv.z * w2.y + xv.w * w3.y;
                a.z += xv.x * w0.z + xv.y * w1.z + xv.z * w2.z + xv.w * w3.z;
                a.w += xv.x * w0.w + xv.y * w1.w + xv.z * w2.w + xv.w * w3.w;
            }
            const int rg = g * G_TILE + r;
            float rs = rsq_out[rg];
            ushort4 o;
            o.x = f2bf(a.x * rs); o.y = f2bf(a.y * rs);
            o.z = f2bf(a.z * rs); o.w = f2bf(a.w * rs);
            ((ushort4*)sxw)[(long)rg * 16 + c4] = o;       // coalesced 8B
        }
    }
}

// ---- Kernel 4: gather-sum per dst node (baseline-identical) ----
#define ACC8(u)                                   \
    a0 += __uint_as_float((u).x << 16);           \
    a1 += __uint_as_float((u).x & 0xFFFF0000u);   \
    a2 += __uint_as_float((u).y << 16);           \
    a3 += __uint_as_float((u).y & 0xFFFF0000u);   \
    a4 += __uint_as_float((u).z << 16);           \
    a5 += __uint_as_float((u).z & 0xFFFF0000u);   \
    a6 += __uint_as_float((u).w << 16);           \
    a7 += __uint_as_float((u).w & 0xFFFF0000u);

__global__ __launch_bounds__(256) void gather_kernel(
        const int* __restrict__ row_beg, const int* __restrict__ row_deg,
        const unsigned* __restrict__ csr_src, const uint4* __restrict__ sxw4,
        const float* __restrict__ b, float* __restrict__ out) {
    const int lane = threadIdx.x & 63;
    const int node = blockIdx.x * 4 + (threadIdx.x >> 6);

    const int eo = lane >> 3;     // edge slot 0..7
    const int c  = lane & 7;      // uint4 index within row (8 cols)

    const int beg = row_beg[node];
    const int deg = row_deg[node];
    const int end = beg + deg;

    float a0 = 0, a1 = 0, a2 = 0, a3 = 0, a4 = 0, a5 = 0, a6 = 0, a7 = 0;

    int j = beg;
    for (; j + 32 <= end; j += 32) {            // 4 row-loads in flight
        unsigned s0 = csr_src[j + eo];
        unsigned s1 = csr_src[j + 8 + eo];
        unsigned s2 = csr_src[j + 16 + eo];
        unsigned s3 = csr_src[j + 24 + eo];
        uint4 u0 = sxw4[(long)s0 * 8 + c];
        uint4 u1 = sxw4[(long)s1 * 8 + c];
        uint4 u2 = sxw4[(long)s2 * 8 + c];
        uint4 u3 = sxw4[(long)s3 * 8 + c];
        ACC8(u0) ACC8(u1) ACC8(u2) ACC8(u3)
    }
    for (; j + 8 <= end; j += 8) {
        unsigned s = csr_src[j + eo];
        uint4 u = sxw4[(long)s * 8 + c];
        ACC8(u)
    }
    if (j < end) {
        int e = j + eo;
        if (e < end) {
            unsigned s = csr_src[e];
            uint4 u = sxw4[(long)s * 8 + c];
            ACC8(u)
        }
    }

    #pragma unroll
    for (int off = 8; off < 64; off <<= 1) {
        a0 += __shfl_xor(a0, off);
        a1 += __shfl_xor(a1, off);
        a2 += __shfl_xor(a2, off);
        a3 += __shfl_xor(a3, off);
        a4 += __shfl_xor(a4, off);
        a5 += __shfl_xor(a5, off);
        a6 += __shfl_xor(a6, off);
        a7 += __shfl_xor(a7, off);
    }

    if (lane < 8) {
        float d = (float)(deg < 1 ? 1 : deg);
        float s = rsqrtf(d);
        float4 b0 = ((const float4*)b)[c * 2];
        float4 b1 = ((const float4*)b)[c * 2 + 1];
        float4 o0, o1;
        o0.x = a0 * s + b0.x; o0.x = o0.x > 0.0f ? o0.x : 0.0f;
        o0.y = a1 * s + b0.y; o0.y = o0.y > 0.0f ? o0.y : 0.0f;
        o0.z = a2 * s + b0.z; o0.z = o0.z > 0.0f ? o0.z : 0.0f;
        o0.w = a3 * s + b0.w; o0.w = o0.w > 0.0f ? o0.w : 0.0f;
        o1.x = a4 * s + b1.x; o1.x = o1.x > 0.0f ? o1.x : 0.0f;
        o1.y = a5 * s + b1.y; o1.y = o1.y > 0.0f ? o1.y : 0.0f;
        o1.z = a6 * s + b1.z; o1.z = o1.z > 0.0f ? o1.z : 0.0f;
        o1.w = a7 * s + b1.w; o1.w = o1.w > 0.0f ? o1.w : 0.0f;
        float4* orow = (float4*)(out + (long)node * OUT_F);
        orow[c * 2]     = o0;
        orow[c * 2 + 1] = o1;
    }
}

extern "C" void kernel_launch(void* const* d_in, const int* in_sizes, int n_in,
                              void* d_out, int out_size, void* d_ws, size_t ws_size,
                              hipStream_t stream) {
    const float* in_feat = (const float*)d_in[0];
    const int*   src     = (const int*)d_in[1];
    const int*   dst     = (const int*)d_in[2];
    const float* W       = (const float*)d_in[3];
    const float* b       = (const float*)d_in[4];
    float*       out     = (float*)d_out;

    // ws layout (31.6 MB):
    //   sxw bf16 [N*64] (12.8MB) | deg4 [4*N] (1.6MB) | bucket_cnt [400 pad]
    // | rsq_out [N] | row_beg [N] | row_deg [N] | pairs [NB*CAPB u32] (16.0MB)
    __hip_bfloat16* sxw        = (__hip_bfloat16*)d_ws;
    int*            deg4       = (int*)(sxw + (size_t)N_NODES * OUT_F);
    int*            bucket_cnt = deg4 + (size_t)NREP * N_NODES;
    float*          rsq_out    = (float*)(bucket_cnt + 400);
    int*            row_beg    = (int*)(rsq_out + N_NODES);
    int*            row_deg    = row_beg + N_NODES;
    unsigned*       pairs      = (unsigned*)(row_deg + N_NODES);

    // zero deg replicas + bucket_cnt (contiguous)
    hipMemsetAsync(deg4, 0, ((size_t)NREP * N_NODES + 400) * sizeof(int), stream);

    partition_kernel<<<C_BLOCKS, 512, 0, stream>>>(src, dst, bucket_cnt,
                                                   pairs, deg4);

    rsq_kernel<<<(N_NODES + 255) / 256, 256, 0, stream>>>(deg4, rsq_out);

    mega_kernel<<<NB + G_BLOCKS, 512, 0, stream>>>(pairs, bucket_cnt,
                                                   row_beg, row_deg,
                                                   in_feat, W, rsq_out, sxw);

    gather_kernel<<<N_NODES / 4, 256, 0, stream>>>(row_beg, row_deg, pairs,
                                                   (const uint4*)sxw, b, out);
}

// Round 6
// 271.605 us; speedup vs baseline: 7.7936x; 1.3644x over previous
//
#include <hip/hip_runtime.h>
#include <hip/hip_bf16.h>

// GCN GraphConv (norm='both', mult-first): out = relu( D_in^-1/2 * A * D_out^-1/2 * (X W) + b )
// N=100000 nodes, E=3200000 edges, IN=128, OUT=64, fp32 in/out.
//
// R17 = verified 260us R0 pipeline with count folded into mega:
//  1. partition: R0-identical dual counting sort (dst pairs + src bytes).
//     NO global atomics (R16 measured: 3.2M device-scope atomics = +90us, 119MB WRITE).
//  2. mega: three independent block ranges, co-resident:
//     [0,NB)        csr counting sort        (R0-identical)
//     [NB,2NB)      count: per-src-bucket histogram -> rsq_out f32 (was count_kernel)
//     [2NB,2NB+1024) gemm: XW -> UNSCALED bf16 sxw (R16-verified float4 loop)
//  3. gather: R0 loop + per-edge rs = rsq_out[s] multiply (400KB, L2-resident;
//     R14-verified numerics, absmax 0.00390625).

constexpr int N_NODES = 100000;
constexpr int N_EDGES = 3200000;
constexpr int IN_F    = 128;
constexpr int OUT_F   = 64;
constexpr int BUCKET_NODES = 256;
constexpr int NB   = (N_NODES + BUCKET_NODES - 1) / BUCKET_NODES;  // 391
constexpr int CAPB = 10240;          // bucket capacity; mean 8184, sd~90 -> 22 sigma
constexpr int C_CHUNK  = 4096;
constexpr int C_BLOCKS = (N_EDGES + C_CHUNK - 1) / C_CHUNK;        // 782 (last cn=1024, %4==0)
constexpr int G_TILE   = 32;         // gemm rows per block-iteration
constexpr int G_BLOCKS = 1024;
constexpr int G_GROUPS = N_NODES / G_TILE;                         // 3125
constexpr int XLS      = 136;        // padded x-tile row stride (floats)

static __device__ __forceinline__ unsigned short f2bf(float f) {
    unsigned u = __float_as_uint(f);
    u += 0x7fffu + ((u >> 16) & 1u);
    return (unsigned short)(u >> 16);
}

// ---- Kernel 1: dual partition (dst pairs + src bytes) — R0-identical ----
__global__ __launch_bounds__(512) void partition_kernel(
        const int* __restrict__ src, const int* __restrict__ dst,
        int* __restrict__ bucket_cnt, int* __restrict__ bucket_cnt2,
        unsigned* __restrict__ pairs, unsigned char* __restrict__ sbytes) {
    __shared__ int l_cnt [NB], l_base [NB], l_pos [NB], g_base [NB];
    __shared__ int l_cnt2[NB], l_base2[NB], l_pos2[NB], g_base2[NB];
    __shared__ int wsum_s[8];
    __shared__ unsigned buf[C_CHUNK];             // 16 KB (dst-sorted pairs)
    __shared__ unsigned short bkt_of[C_CHUNK];    // 8 KB
    __shared__ unsigned char  bbuf[C_CHUNK];      // 4 KB (src-sorted local ids)
    __shared__ unsigned short bkt2_of[C_CHUNK];   // 8 KB
    const int tid  = threadIdx.x;
    const int lane = tid & 63;
    const int wid  = tid >> 6;                    // 0..7
    const long e0 = (long)blockIdx.x * C_CHUNK;
    const int  cn = (int)min((long)C_CHUNK, (long)N_EDGES - e0);
    const int  cn4 = cn >> 2;                     // cn is always a multiple of 4

    for (int i = tid; i < NB; i += 512) { l_cnt[i] = 0; l_cnt2[i] = 0; }
    __syncthreads();

    // load edges as int4 (4 edges per load), count both key spaces
    unsigned r_pk[8];
    short    r_bk[8];
    const int4* d4p = (const int4*)(dst + e0);
    const int4* s4p = (const int4*)(src + e0);
    #pragma unroll
    for (int k = 0; k < 2; ++k) {
        int i4 = tid + k * 512;
        int rb = k * 4;
        if (i4 < cn4) {
            int4 d4 = d4p[i4];
            int4 s4 = s4p[i4];
            int dd[4] = {d4.x, d4.y, d4.z, d4.w};
            int ss[4] = {s4.x, s4.y, s4.z, s4.w};
            #pragma unroll
            for (int j = 0; j < 4; ++j) {
                int bk = dd[j] >> 8;
                r_bk[rb + j] = (short)bk;
                r_pk[rb + j] = ((unsigned)(dd[j] & 255) << 17) | (unsigned)ss[j];
                atomicAdd(&l_cnt[bk], 1);
                atomicAdd(&l_cnt2[ss[j] >> 8], 1);
            }
        } else {
            #pragma unroll
            for (int j = 0; j < 4; ++j) r_bk[rb + j] = -1;
        }
    }
    __syncthreads();

    {   // scan 1: dst buckets -> l_base/l_pos, reserve global runs
        int v = (tid < NB) ? l_cnt[tid] : 0;
        int inc = v;
        #pragma unroll
        for (int off = 1; off < 64; off <<= 1) {
            int t = __shfl_up(inc, off);
            if (lane >= off) inc += t;
        }
        if (lane == 63) wsum_s[wid] = inc;
        __syncthreads();
        int woff = 0;
        #pragma unroll
        for (int w = 0; w < 8; ++w) if (w < wid) woff += wsum_s[w];
        int excl = woff + inc - v;
        if (tid < NB) {
            l_base[tid] = excl;
            l_pos[tid]  = excl;
            g_base[tid] = v ? atomicAdd(&bucket_cnt[tid], v) : 0;
        }
    }
    __syncthreads();
    {   // scan 2: src buckets
        int v = (tid < NB) ? l_cnt2[tid] : 0;
        int inc = v;
        #pragma unroll
        for (int off = 1; off < 64; off <<= 1) {
            int t = __shfl_up(inc, off);
            if (lane >= off) inc += t;
        }
        if (lane == 63) wsum_s[wid] = inc;
        __syncthreads();
        int woff = 0;
        #pragma unroll
        for (int w = 0; w < 8; ++w) if (w < wid) woff += wsum_s[w];
        int excl = woff + inc - v;
        if (tid < NB) {
            l_base2[tid] = excl;
            l_pos2[tid]  = excl;
            g_base2[tid] = v ? atomicAdd(&bucket_cnt2[tid], v) : 0;
        }
    }
    __syncthreads();

    // scatter into LDS: both counting sorts
    #pragma unroll
    for (int k = 0; k < 8; ++k) {
        if (r_bk[k] >= 0) {
            unsigned pk = r_pk[k];
            int p = atomicAdd(&l_pos[(int)r_bk[k]], 1);
            buf[p] = pk;
            bkt_of[p] = (unsigned short)r_bk[k];
            int bk2 = (int)((pk >> 8) & 0x1FF);        // src >> 8
            int p2 = atomicAdd(&l_pos2[bk2], 1);
            bbuf[p2] = (unsigned char)(pk & 255);      // src & 255
            bkt2_of[p2] = (unsigned short)bk2;
        }
    }
    __syncthreads();

    // coalesced flushes
    for (int i = tid; i < cn; i += 512) {
        int bk = bkt_of[i];
        int gp = g_base[bk] + (i - l_base[bk]);
        if (gp < CAPB)                                 // 22-sigma safety
            pairs[(long)bk * CAPB + gp] = buf[i];
        int b2 = bkt2_of[i];
        int gp2 = g_base2[b2] + (i - l_base2[b2]);
        if (gp2 < CAPB)
            sbytes[(long)b2 * CAPB + gp2] = bbuf[i];
    }
}

// ---- Kernel 2 (mega): [0,NB) csr | [NB,2NB) count->rsq | [2NB,..) gemm ----
__global__ __launch_bounds__(512) void mega_kernel(
        unsigned* __restrict__ pairs, const int* __restrict__ bucket_cnt,
        const unsigned char* __restrict__ sbytes, const int* __restrict__ bucket_cnt2,
        int* __restrict__ row_beg, int* __restrict__ row_deg,
        float* __restrict__ rsq_out,
        const float* __restrict__ x, const float* __restrict__ W,
        __hip_bfloat16* __restrict__ sxw) {
    alignas(16) __shared__ char smem[50176];       // union: csr 43KB | count 1KB | gemm 49KB
    const int tid = threadIdx.x;

    if (blockIdx.x < NB) {
        // ---------------- csr path (R0-identical) ----------------
        unsigned* buf  = (unsigned*)smem;                    // 40960 B
        int*      hist = (int*)(smem + 40960);               // 1024 B
        int*      cur  = (int*)(smem + 40960 + 1024);        // 1024 B
        int*      wsum = (int*)(smem + 40960 + 2048);        // 16 B
        const int lane = tid & 63;
        const int wid  = tid >> 6;
        const int bk   = blockIdx.x;
        const long base = (long)bk * CAPB;
        const int cnt  = min(bucket_cnt[bk], CAPB);

        if (tid < 256) hist[tid] = 0;
        __syncthreads();

        const int c4 = cnt >> 2;
        const uint4* p4 = (const uint4*)(pairs + base);
        for (int i4 = tid; i4 < c4; i4 += 512) {
            uint4 e4 = p4[i4];
            ((uint4*)buf)[i4] = e4;                           // ds_write_b128
            atomicAdd(&hist[e4.x >> 17], 1);
            atomicAdd(&hist[e4.y >> 17], 1);
            atomicAdd(&hist[e4.z >> 17], 1);
            atomicAdd(&hist[e4.w >> 17], 1);
        }
        for (int i = (c4 << 2) + tid; i < cnt; i += 512) {
            unsigned e = pairs[base + i];
            buf[i] = e;
            atomicAdd(&hist[e >> 17], 1);
        }
        __syncthreads();

        int v = (tid < 256) ? hist[tid] : 0;
        int inc = v;
        #pragma unroll
        for (int off = 1; off < 64; off <<= 1) {
            int t = __shfl_up(inc, off);
            if (lane >= off) inc += t;
        }
        if (tid < 256 && lane == 63) wsum[wid] = inc;
        __syncthreads();
        if (tid < 256) {
            int woff = 0;
            #pragma unroll
            for (int w = 0; w < 4; ++w) if (w < wid) woff += wsum[w];
            int excl = woff + inc - v;
            cur[tid] = excl;
            const int node = bk * BUCKET_NODES + tid;
            if (node < N_NODES) {
                row_beg[node] = (int)(base + excl);
                row_deg[node] = v;
            }
        }
        __syncthreads();

        for (int i = tid; i < cnt; i += 512) {
            unsigned e = buf[i];
            int p = atomicAdd(&cur[e >> 17], 1);
            pairs[base + p] = e & 0x1FFFF;   // plain src, node-sorted
        }
    } else if (blockIdx.x < 2 * NB) {
        // ---------------- count path: src-bucket histogram -> rsq_out ----------------
        int* hist = (int*)smem;                    // 1024 B
        const int bk = blockIdx.x - NB;
        if (tid < 256) hist[tid] = 0;
        __syncthreads();

        const int cnt = min(bucket_cnt2[bk], CAPB);
        const unsigned* sb4 = (const unsigned*)(sbytes + (long)bk * CAPB);
        const int n4 = cnt >> 2;
        for (int i = tid; i < n4; i += 512) {
            unsigned u = sb4[i];
            atomicAdd(&hist[u & 255], 1);
            atomicAdd(&hist[(u >> 8) & 255], 1);
            atomicAdd(&hist[(u >> 16) & 255], 1);
            atomicAdd(&hist[u >> 24], 1);
        }
        for (int i = (n4 << 2) + tid; i < cnt; i += 512)
            atomicAdd(&hist[sbytes[(long)bk * CAPB + i]], 1);
        __syncthreads();

        if (tid < 256) {
            const int node = bk * BUCKET_NODES + tid;
            if (node < N_NODES) {
                int d = hist[tid];
                rsq_out[node] = rsqrtf((float)(d < 1 ? 1 : d));
            }
        }
    } else {
        // ---------------- gemm path: sxw = bf16(X W), UNSCALED ----------------
        float* Wl = (float*)smem;                  // 32768 B  [128][64]
        float* xl = (float*)(smem + 32768);        // 17408 B  [32][136] padded
        for (int i = tid; i < IN_F * OUT_F; i += 512) Wl[i] = W[i];

        const int r  = tid >> 4;                   // 0..31 row
        const int c4 = tid & 15;                   // 0..15 col quad
        const float4* Wl4 = (const float4*)Wl;
        const int bid = blockIdx.x - 2 * NB;

        for (int g = bid; g < G_GROUPS; g += G_BLOCKS) {
            __syncthreads();                       // protect xl (and Wl on iter 0)
            const float4* xg = (const float4*)(x + (long)g * G_TILE * IN_F);
            #pragma unroll
            for (int k = 0; k < 2; ++k) {
                int i = tid + k * 512;
                int row = i >> 5, q = i & 31;
                ((float4*)xl)[row * (XLS / 4) + q] = xg[i];
            }
            __syncthreads();

            float4 a = {0.0f, 0.0f, 0.0f, 0.0f};
            const float4* xr4 = (const float4*)(xl + r * XLS);
            #pragma unroll
            for (int k4 = 0; k4 < IN_F / 4; ++k4) {
                float4 xv = xr4[k4];                       // conflict-free (pad)
                float4 w0 = Wl4[(k4 * 4 + 0) * 16 + c4];   // broadcast groups, free
                float4 w1 = Wl4[(k4 * 4 + 1) * 16 + c4];
                float4 w2 = Wl4[(k4 * 4 + 2) * 16 + c4];
                float4 w3 = Wl4[(k4 * 4 + 3) * 16 + c4];
                a.x += xv.x * w0.x + xv.y * w1.x + xv.z * w2.x + xv.w * w3.x;
                a.y += xv.x * w0.y + xv.y * w1.y + xv.z * w2.y + xv.w * w3.y;
                a.z += xv.x * w0.z + xv.y * w1.z + xv.z * w2.z + xv.w * w3.z;
                a.w += xv.x * w0.w + xv.y * w1.w + xv.z * w2.w + xv.w * w3.w;
            }
            const int rg = g * G_TILE + r;
            ushort4 o;
            o.x = f2bf(a.x); o.y = f2bf(a.y); o.z = f2bf(a.z); o.w = f2bf(a.w);
            ((ushort4*)sxw)[(long)rg * 16 + c4] = o;       // coalesced 8B
        }
    }
}

// ---- Kernel 3: gather-sum per dst node + per-edge rsq_out scale ----
#define ACC8R(u, rs) {                                          \
    a0 = fmaf(__uint_as_float((u).x << 16),         (rs), a0);  \
    a1 = fmaf(__uint_as_float((u).x & 0xFFFF0000u), (rs), a1);  \
    a2 = fmaf(__uint_as_float((u).y << 16),         (rs), a2);  \
    a3 = fmaf(__uint_as_float((u).y & 0xFFFF0000u), (rs), a3);  \
    a4 = fmaf(__uint_as_float((u).z << 16),         (rs), a4);  \
    a5 = fmaf(__uint_as_float((u).z & 0xFFFF0000u), (rs), a5);  \
    a6 = fmaf(__uint_as_float((u).w << 16),         (rs), a6);  \
    a7 = fmaf(__uint_as_float((u).w & 0xFFFF0000u), (rs), a7);  \
}

__global__ __launch_bounds__(256) void gather_kernel(
        const int* __restrict__ row_beg, const int* __restrict__ row_deg,
        const unsigned* __restrict__ csr_src, const uint4* __restrict__ sxw4,
        const float* __restrict__ rsq_out,
        const float* __restrict__ b, float* __restrict__ out) {
    const int lane = threadIdx.x & 63;
    const int node = blockIdx.x * 4 + (threadIdx.x >> 6);

    const int eo = lane >> 3;     // edge slot 0..7
    const int c  = lane & 7;      // uint4 index within row (8 cols)

    const int beg = row_beg[node];
    const int deg = row_deg[node];
    const int end = beg + deg;

    float a0 = 0, a1 = 0, a2 = 0, a3 = 0, a4 = 0, a5 = 0, a6 = 0, a7 = 0;

    int j = beg;
    for (; j + 32 <= end; j += 32) {            // 4 row-loads in flight
        unsigned s0 = csr_src[j + eo];
        unsigned s1 = csr_src[j + 8 + eo];
        unsigned s2 = csr_src[j + 16 + eo];
        unsigned s3 = csr_src[j + 24 + eo];
        float r0 = rsq_out[s0], r1 = rsq_out[s1];
        float r2 = rsq_out[s2], r3 = rsq_out[s3];
        uint4 u0 = sxw4[(long)s0 * 8 + c];
        uint4 u1 = sxw4[(long)s1 * 8 + c];
        uint4 u2 = sxw4[(long)s2 * 8 + c];
        uint4 u3 = sxw4[(long)s3 * 8 + c];
        ACC8R(u0, r0) ACC8R(u1, r1) ACC8R(u2, r2) ACC8R(u3, r3)
    }
    for (; j + 8 <= end; j += 8) {
        unsigned s = csr_src[j + eo];
        float rs = rsq_out[s];
        uint4 u = sxw4[(long)s * 8 + c];
        ACC8R(u, rs)
    }
    if (j < end) {
        int e = j + eo;
        if (e < end) {
            unsigned s = csr_src[e];
            float rs = rsq_out[s];
            uint4 u = sxw4[(long)s * 8 + c];
            ACC8R(u, rs)
        }
    }

    #pragma unroll
    for (int off = 8; off < 64; off <<= 1) {
        a0 += __shfl_xor(a0, off);
        a1 += __shfl_xor(a1, off);
        a2 += __shfl_xor(a2, off);
        a3 += __shfl_xor(a3, off);
        a4 += __shfl_xor(a4, off);
        a5 += __shfl_xor(a5, off);
        a6 += __shfl_xor(a6, off);
        a7 += __shfl_xor(a7, off);
    }

    if (lane < 8) {
        float d = (float)(deg < 1 ? 1 : deg);
        float s = rsqrtf(d);
        float4 b0 = ((const float4*)b)[c * 2];
        float4 b1 = ((const float4*)b)[c * 2 + 1];
        float4 o0, o1;
        o0.x = a0 * s + b0.x; o0.x = o0.x > 0.0f ? o0.x : 0.0f;
        o0.y = a1 * s + b0.y; o0.y = o0.y > 0.0f ? o0.y : 0.0f;
        o0.z = a2 * s + b0.z; o0.z = o0.z > 0.0f ? o0.z : 0.0f;
        o0.w = a3 * s + b0.w; o0.w = o0.w > 0.0f ? o0.w : 0.0f;
        o1.x = a4 * s + b1.x; o1.x = o1.x > 0.0f ? o1.x : 0.0f;
        o1.y = a5 * s + b1.y; o1.y = o1.y > 0.0f ? o1.y : 0.0f;
        o1.z = a6 * s + b1.z; o1.z = o1.z > 0.0f ? o1.z : 0.0f;
        o1.w = a7 * s + b1.w; o1.w = o1.w > 0.0f ? o1.w : 0.0f;
        float4* orow = (float4*)(out + (long)node * OUT_F);
        orow[c * 2]     = o0;
        orow[c * 2 + 1] = o1;
    }
}

extern "C" void kernel_launch(void* const* d_in, const int* in_sizes, int n_in,
                              void* d_out, int out_size, void* d_ws, size_t ws_size,
                              hipStream_t stream) {
    const float* in_feat = (const float*)d_in[0];
    const int*   src     = (const int*)d_in[1];
    const int*   dst     = (const int*)d_in[2];
    const float* W       = (const float*)d_in[3];
    const float* b       = (const float*)d_in[4];
    float*       out     = (float*)d_out;

    // ws: sxw bf16 [N*64] (12.8MB) | rsq_out [N] | bucket_cnt [NB] | bucket_cnt2 [NB]
    //   | row_beg [N] | row_deg [N] | pairs [NB*CAPB u32] (16MB) | sbytes [NB*CAPB] (4MB)
    __hip_bfloat16* sxw         = (__hip_bfloat16*)d_ws;
    float*          rsq_out     = (float*)(sxw + (size_t)N_NODES * OUT_F);
    int*            bucket_cnt  = (int*)(rsq_out + N_NODES);
    int*            bucket_cnt2 = bucket_cnt + NB;
    int*            row_beg     = bucket_cnt2 + NB;
    int*            row_deg     = row_beg + N_NODES;
    unsigned*       pairs       = (unsigned*)(row_deg + N_NODES);
    unsigned char*  sbytes      = (unsigned char*)(pairs + (size_t)NB * CAPB);

    hipMemsetAsync(bucket_cnt, 0, 2 * (size_t)NB * sizeof(int), stream);

    partition_kernel<<<C_BLOCKS, 512, 0, stream>>>(src, dst, bucket_cnt,
                                                   bucket_cnt2, pairs, sbytes);

    mega_kernel<<<2 * NB + G_BLOCKS, 512, 0, stream>>>(
        pairs, bucket_cnt, sbytes, bucket_cnt2,
        row_beg, row_deg, rsq_out, in_feat, W, sxw);

    gather_kernel<<<N_NODES / 4, 256, 0, stream>>>(row_beg, row_deg, pairs,
                                                   (const uint4*)sxw, rsq_out,
                                                   b, out);
}

// Round 7
// 259.405 us; speedup vs baseline: 8.1601x; 1.0470x over previous
//
#include <hip/hip_runtime.h>
#include <hip/hip_bf16.h>

// GCN GraphConv (norm='both', mult-first): out = relu( D_in^-1/2 * A * D_out^-1/2 * (X W) + b )
// N=100000 nodes, E=3200000 edges, IN=128, OUT=64, fp32 in/out.
//
// R18 = R17 structure with mega's gemm restored to the R0-verified loop:
//  1. partition: R0-identical dual counting sort (dst pairs + src bytes).
//  2. mega: three independent block ranges, co-resident:
//     [0,NB)         csr counting sort                 (R0-identical)
//     [NB,2NB)       count: src-bucket hist -> rsq_out (R17-verified)
//     [2NB,2NB+1024) gemm: XW -> UNSCALED bf16 sxw     (R0-identical loop, VGPR~40)
//  3. gather: R0 loop + per-edge rs = rsq_out[s] multiply (R17-verified).
// R17 lesson: float4-W gemm loop -> VGPR 108, occupancy 19%, mega 68->82us.
// Same LDS bytes/FMA as scalar-W form; occupancy is what matters. Reverted.

constexpr int N_NODES = 100000;
constexpr int N_EDGES = 3200000;
constexpr int IN_F    = 128;
constexpr int OUT_F   = 64;
constexpr int BUCKET_NODES = 256;
constexpr int NB   = (N_NODES + BUCKET_NODES - 1) / BUCKET_NODES;  // 391
constexpr int CAPB = 10240;          // bucket capacity; mean 8184, sd~90 -> 22 sigma
constexpr int C_CHUNK  = 4096;
constexpr int C_BLOCKS = (N_EDGES + C_CHUNK - 1) / C_CHUNK;        // 782 (last cn=1024, %4==0)
constexpr int G_TILE   = 32;         // gemm rows per block-iteration
constexpr int G_BLOCKS = 1024;
constexpr int G_GROUPS = N_NODES / G_TILE;                         // 3125

// ---- Kernel 1: dual partition (dst pairs + src bytes) — R0-identical ----
__global__ __launch_bounds__(512) void partition_kernel(
        const int* __restrict__ src, const int* __restrict__ dst,
        int* __restrict__ bucket_cnt, int* __restrict__ bucket_cnt2,
        unsigned* __restrict__ pairs, unsigned char* __restrict__ sbytes) {
    __shared__ int l_cnt [NB], l_base [NB], l_pos [NB], g_base [NB];
    __shared__ int l_cnt2[NB], l_base2[NB], l_pos2[NB], g_base2[NB];
    __shared__ int wsum_s[8];
    __shared__ unsigned buf[C_CHUNK];             // 16 KB (dst-sorted pairs)
    __shared__ unsigned short bkt_of[C_CHUNK];    // 8 KB
    __shared__ unsigned char  bbuf[C_CHUNK];      // 4 KB (src-sorted local ids)
    __shared__ unsigned short bkt2_of[C_CHUNK];   // 8 KB
    const int tid  = threadIdx.x;
    const int lane = tid & 63;
    const int wid  = tid >> 6;                    // 0..7
    const long e0 = (long)blockIdx.x * C_CHUNK;
    const int  cn = (int)min((long)C_CHUNK, (long)N_EDGES - e0);
    const int  cn4 = cn >> 2;                     // cn is always a multiple of 4

    for (int i = tid; i < NB; i += 512) { l_cnt[i] = 0; l_cnt2[i] = 0; }
    __syncthreads();

    // load edges as int4 (4 edges per load), count both key spaces
    unsigned r_pk[8];
    short    r_bk[8];
    const int4* d4p = (const int4*)(dst + e0);
    const int4* s4p = (const int4*)(src + e0);
    #pragma unroll
    for (int k = 0; k < 2; ++k) {
        int i4 = tid + k * 512;
        int rb = k * 4;
        if (i4 < cn4) {
            int4 d4 = d4p[i4];
            int4 s4 = s4p[i4];
            int dd[4] = {d4.x, d4.y, d4.z, d4.w};
            int ss[4] = {s4.x, s4.y, s4.z, s4.w};
            #pragma unroll
            for (int j = 0; j < 4; ++j) {
                int bk = dd[j] >> 8;
                r_bk[rb + j] = (short)bk;
                r_pk[rb + j] = ((unsigned)(dd[j] & 255) << 17) | (unsigned)ss[j];
                atomicAdd(&l_cnt[bk], 1);
                atomicAdd(&l_cnt2[ss[j] >> 8], 1);
            }
        } else {
            #pragma unroll
            for (int j = 0; j < 4; ++j) r_bk[rb + j] = -1;
        }
    }
    __syncthreads();

    {   // scan 1: dst buckets -> l_base/l_pos, reserve global runs
        int v = (tid < NB) ? l_cnt[tid] : 0;
        int inc = v;
        #pragma unroll
        for (int off = 1; off < 64; off <<= 1) {
            int t = __shfl_up(inc, off);
            if (lane >= off) inc += t;
        }
        if (lane == 63) wsum_s[wid] = inc;
        __syncthreads();
        int woff = 0;
        #pragma unroll
        for (int w = 0; w < 8; ++w) if (w < wid) woff += wsum_s[w];
        int excl = woff + inc - v;
        if (tid < NB) {
            l_base[tid] = excl;
            l_pos[tid]  = excl;
            g_base[tid] = v ? atomicAdd(&bucket_cnt[tid], v) : 0;
        }
    }
    __syncthreads();
    {   // scan 2: src buckets
        int v = (tid < NB) ? l_cnt2[tid] : 0;
        int inc = v;
        #pragma unroll
        for (int off = 1; off < 64; off <<= 1) {
            int t = __shfl_up(inc, off);
            if (lane >= off) inc += t;
        }
        if (lane == 63) wsum_s[wid] = inc;
        __syncthreads();
        int woff = 0;
        #pragma unroll
        for (int w = 0; w < 8; ++w) if (w < wid) woff += wsum_s[w];
        int excl = woff + inc - v;
        if (tid < NB) {
            l_base2[tid] = excl;
            l_pos2[tid]  = excl;
            g_base2[tid] = v ? atomicAdd(&bucket_cnt2[tid], v) : 0;
        }
    }
    __syncthreads();

    // scatter into LDS: both counting sorts
    #pragma unroll
    for (int k = 0; k < 8; ++k) {
        if (r_bk[k] >= 0) {
            unsigned pk = r_pk[k];
            int p = atomicAdd(&l_pos[(int)r_bk[k]], 1);
            buf[p] = pk;
            bkt_of[p] = (unsigned short)r_bk[k];
            int bk2 = (int)((pk >> 8) & 0x1FF);        // src >> 8
            int p2 = atomicAdd(&l_pos2[bk2], 1);
            bbuf[p2] = (unsigned char)(pk & 255);      // src & 255
            bkt2_of[p2] = (unsigned short)bk2;
        }
    }
    __syncthreads();

    // coalesced flushes
    for (int i = tid; i < cn; i += 512) {
        int bk = bkt_of[i];
        int gp = g_base[bk] + (i - l_base[bk]);
        if (gp < CAPB)                                 // 22-sigma safety
            pairs[(long)bk * CAPB + gp] = buf[i];
        int b2 = bkt2_of[i];
        int gp2 = g_base2[b2] + (i - l_base2[b2]);
        if (gp2 < CAPB)
            sbytes[(long)b2 * CAPB + gp2] = bbuf[i];
    }
}

// ---- Kernel 2 (mega): [0,NB) csr | [NB,2NB) count->rsq | [2NB,..) gemm ----
__global__ __launch_bounds__(512) void mega_kernel(
        unsigned* __restrict__ pairs, const int* __restrict__ bucket_cnt,
        const unsigned char* __restrict__ sbytes, const int* __restrict__ bucket_cnt2,
        int* __restrict__ row_beg, int* __restrict__ row_deg,
        float* __restrict__ rsq_out,
        const float* __restrict__ x, const float* __restrict__ W,
        __hip_bfloat16* __restrict__ sxw) {
    alignas(16) __shared__ char smem[49152];       // union: csr 43KB | count 1KB | gemm 48KB
    const int tid = threadIdx.x;

    if (blockIdx.x < NB) {
        // ---------------- csr path (R0-identical) ----------------
        unsigned* buf  = (unsigned*)smem;                    // 40960 B
        int*      hist = (int*)(smem + 40960);               // 1024 B
        int*      cur  = (int*)(smem + 40960 + 1024);        // 1024 B
        int*      wsum = (int*)(smem + 40960 + 2048);        // 16 B
        const int lane = tid & 63;
        const int wid  = tid >> 6;
        const int bk   = blockIdx.x;
        const long base = (long)bk * CAPB;
        const int cnt  = min(bucket_cnt[bk], CAPB);

        if (tid < 256) hist[tid] = 0;
        __syncthreads();

        const int c4 = cnt >> 2;
        const uint4* p4 = (const uint4*)(pairs + base);
        for (int i4 = tid; i4 < c4; i4 += 512) {
            uint4 e4 = p4[i4];
            ((uint4*)buf)[i4] = e4;                           // ds_write_b128
            atomicAdd(&hist[e4.x >> 17], 1);
            atomicAdd(&hist[e4.y >> 17], 1);
            atomicAdd(&hist[e4.z >> 17], 1);
            atomicAdd(&hist[e4.w >> 17], 1);
        }
        for (int i = (c4 << 2) + tid; i < cnt; i += 512) {
            unsigned e = pairs[base + i];
            buf[i] = e;
            atomicAdd(&hist[e >> 17], 1);
        }
        __syncthreads();

        int v = (tid < 256) ? hist[tid] : 0;
        int inc = v;
        #pragma unroll
        for (int off = 1; off < 64; off <<= 1) {
            int t = __shfl_up(inc, off);
            if (lane >= off) inc += t;
        }
        if (tid < 256 && lane == 63) wsum[wid] = inc;
        __syncthreads();
        if (tid < 256) {
            int woff = 0;
            #pragma unroll
            for (int w = 0; w < 4; ++w) if (w < wid) woff += wsum[w];
            int excl = woff + inc - v;
            cur[tid] = excl;
            const int node = bk * BUCKET_NODES + tid;
            if (node < N_NODES) {
                row_beg[node] = (int)(base + excl);
                row_deg[node] = v;
            }
        }
        __syncthreads();

        for (int i = tid; i < cnt; i += 512) {
            unsigned e = buf[i];
            int p = atomicAdd(&cur[e >> 17], 1);
            pairs[base + p] = e & 0x1FFFF;   // plain src, node-sorted
        }
    } else if (blockIdx.x < 2 * NB) {
        // ---------------- count path: src-bucket histogram -> rsq_out ----------------
        int* hist = (int*)smem;                    // 1024 B
        const int bk = blockIdx.x - NB;
        if (tid < 256) hist[tid] = 0;
        __syncthreads();

        const int cnt = min(bucket_cnt2[bk], CAPB);
        const unsigned* sb4 = (const unsigned*)(sbytes + (long)bk * CAPB);
        const int n4 = cnt >> 2;
        for (int i = tid; i < n4; i += 512) {
            unsigned u = sb4[i];
            atomicAdd(&hist[u & 255], 1);
            atomicAdd(&hist[(u >> 8) & 255], 1);
            atomicAdd(&hist[(u >> 16) & 255], 1);
            atomicAdd(&hist[u >> 24], 1);
        }
        for (int i = (n4 << 2) + tid; i < cnt; i += 512)
            atomicAdd(&hist[sbytes[(long)bk * CAPB + i]], 1);
        __syncthreads();

        if (tid < 256) {
            const int node = bk * BUCKET_NODES + tid;
            if (node < N_NODES) {
                int d = hist[tid];
                rsq_out[node] = rsqrtf((float)(d < 1 ? 1 : d));
            }
        }
    } else {
        // ---------------- gemm path (R0-identical loop, unscaled epilogue) ----------------
        float* Wl = (float*)smem;                  // 32768 B
        float* xl = (float*)(smem + 32768);        // 16384 B (32 rows x 128)
        for (int i = tid; i < IN_F * OUT_F; i += 512) Wl[i] = W[i];

        const int sub = tid >> 6;                  // 0..7 -> rows sub*4..sub*4+3
        const int col = tid & 63;
        const int bid = blockIdx.x - 2 * NB;

        for (int g = bid; g < G_GROUPS; g += G_BLOCKS) {
            __syncthreads();
            const float4* xg = (const float4*)(x + (long)g * G_TILE * IN_F);
            float4* xl4 = (float4*)xl;
            xl4[tid]       = xg[tid];
            xl4[tid + 512] = xg[tid + 512];
            __syncthreads();

            float a0 = 0.0f, a1 = 0.0f, a2 = 0.0f, a3 = 0.0f;
            const float* xr = xl + sub * 4 * IN_F;
            #pragma unroll
            for (int k4 = 0; k4 < IN_F / 4; ++k4) {
                float4 x0 = ((const float4*)xr)[k4];
                float4 x1 = ((const float4*)(xr + IN_F))[k4];
                float4 x2 = ((const float4*)(xr + 2 * IN_F))[k4];
                float4 x3 = ((const float4*)(xr + 3 * IN_F))[k4];
                float w0 = Wl[(k4 * 4 + 0) * OUT_F + col];
                float w1 = Wl[(k4 * 4 + 1) * OUT_F + col];
                float w2 = Wl[(k4 * 4 + 2) * OUT_F + col];
                float w3 = Wl[(k4 * 4 + 3) * OUT_F + col];
                a0 += x0.x * w0 + x0.y * w1 + x0.z * w2 + x0.w * w3;
                a1 += x1.x * w0 + x1.y * w1 + x1.z * w2 + x1.w * w3;
                a2 += x2.x * w0 + x2.y * w1 + x2.z * w2 + x2.w * w3;
                a3 += x3.x * w0 + x3.y * w1 + x3.z * w2 + x3.w * w3;
            }

            const int r0 = g * G_TILE + sub * 4;
            sxw[(long)(r0 + 0) * OUT_F + col] = __float2bfloat16(a0);
            sxw[(long)(r0 + 1) * OUT_F + col] = __float2bfloat16(a1);
            sxw[(long)(r0 + 2) * OUT_F + col] = __float2bfloat16(a2);
            sxw[(long)(r0 + 3) * OUT_F + col] = __float2bfloat16(a3);
        }
    }
}

// ---- Kernel 3: gather-sum per dst node + per-edge rsq_out scale ----
#define ACC8R(u, rs) {                                          \
    a0 = fmaf(__uint_as_float((u).x << 16),         (rs), a0);  \
    a1 = fmaf(__uint_as_float((u).x & 0xFFFF0000u), (rs), a1);  \
    a2 = fmaf(__uint_as_float((u).y << 16),         (rs), a2);  \
    a3 = fmaf(__uint_as_float((u).y & 0xFFFF0000u), (rs), a3);  \
    a4 = fmaf(__uint_as_float((u).z << 16),         (rs), a4);  \
    a5 = fmaf(__uint_as_float((u).z & 0xFFFF0000u), (rs), a5);  \
    a6 = fmaf(__uint_as_float((u).w << 16),         (rs), a6);  \
    a7 = fmaf(__uint_as_float((u).w & 0xFFFF0000u), (rs), a7);  \
}

__global__ __launch_bounds__(256) void gather_kernel(
        const int* __restrict__ row_beg, const int* __restrict__ row_deg,
        const unsigned* __restrict__ csr_src, const uint4* __restrict__ sxw4,
        const float* __restrict__ rsq_out,
        const float* __restrict__ b, float* __restrict__ out) {
    const int lane = threadIdx.x & 63;
    const int node = blockIdx.x * 4 + (threadIdx.x >> 6);

    const int eo = lane >> 3;     // edge slot 0..7
    const int c  = lane & 7;      // uint4 index within row (8 cols)

    const int beg = row_beg[node];
    const int deg = row_deg[node];
    const int end = beg + deg;

    float a0 = 0, a1 = 0, a2 = 0, a3 = 0, a4 = 0, a5 = 0, a6 = 0, a7 = 0;

    int j = beg;
    for (; j + 32 <= end; j += 32) {            // 4 row-loads in flight
        unsigned s0 = csr_src[j + eo];
        unsigned s1 = csr_src[j + 8 + eo];
        unsigned s2 = csr_src[j + 16 + eo];
        unsigned s3 = csr_src[j + 24 + eo];
        float r0 = rsq_out[s0], r1 = rsq_out[s1];
        float r2 = rsq_out[s2], r3 = rsq_out[s3];
        uint4 u0 = sxw4[(long)s0 * 8 + c];
        uint4 u1 = sxw4[(long)s1 * 8 + c];
        uint4 u2 = sxw4[(long)s2 * 8 + c];
        uint4 u3 = sxw4[(long)s3 * 8 + c];
        ACC8R(u0, r0) ACC8R(u1, r1) ACC8R(u2, r2) ACC8R(u3, r3)
    }
    for (; j + 8 <= end; j += 8) {
        unsigned s = csr_src[j + eo];
        float rs = rsq_out[s];
        uint4 u = sxw4[(long)s * 8 + c];
        ACC8R(u, rs)
    }
    if (j < end) {
        int e = j + eo;
        if (e < end) {
            unsigned s = csr_src[e];
            float rs = rsq_out[s];
            uint4 u = sxw4[(long)s * 8 + c];
            ACC8R(u, rs)
        }
    }

    #pragma unroll
    for (int off = 8; off < 64; off <<= 1) {
        a0 += __shfl_xor(a0, off);
        a1 += __shfl_xor(a1, off);
        a2 += __shfl_xor(a2, off);
        a3 += __shfl_xor(a3, off);
        a4 += __shfl_xor(a4, off);
        a5 += __shfl_xor(a5, off);
        a6 += __shfl_xor(a6, off);
        a7 += __shfl_xor(a7, off);
    }

    if (lane < 8) {
        float d = (float)(deg < 1 ? 1 : deg);
        float s = rsqrtf(d);
        float4 b0 = ((const float4*)b)[c * 2];
        float4 b1 = ((const float4*)b)[c * 2 + 1];
        float4 o0, o1;
        o0.x = a0 * s + b0.x; o0.x = o0.x > 0.0f ? o0.x : 0.0f;
        o0.y = a1 * s + b0.y; o0.y = o0.y > 0.0f ? o0.y : 0.0f;
        o0.z = a2 * s + b0.z; o0.z = o0.z > 0.0f ? o0.z : 0.0f;
        o0.w = a3 * s + b0.w; o0.w = o0.w > 0.0f ? o0.w : 0.0f;
        o1.x = a4 * s + b1.x; o1.x = o1.x > 0.0f ? o1.x : 0.0f;
        o1.y = a5 * s + b1.y; o1.y = o1.y > 0.0f ? o1.y : 0.0f;
        o1.z = a6 * s + b1.z; o1.z = o1.z > 0.0f ? o1.z : 0.0f;
        o1.w = a7 * s + b1.w; o1.w = o1.w > 0.0f ? o1.w : 0.0f;
        float4* orow = (float4*)(out + (long)node * OUT_F);
        orow[c * 2]     = o0;
        orow[c * 2 + 1] = o1;
    }
}

extern "C" void kernel_launch(void* const* d_in, const int* in_sizes, int n_in,
                              void* d_out, int out_size, void* d_ws, size_t ws_size,
                              hipStream_t stream) {
    const float* in_feat = (const float*)d_in[0];
    const int*   src     = (const int*)d_in[1];
    const int*   dst     = (const int*)d_in[2];
    const float* W       = (const float*)d_in[3];
    const float* b       = (const float*)d_in[4];
    float*       out     = (float*)d_out;

    // ws: sxw bf16 [N*64] (12.8MB) | rsq_out [N] | bucket_cnt [NB] | bucket_cnt2 [NB]
    //   | row_beg [N] | row_deg [N] | pairs [NB*CAPB u32] (16MB) | sbytes [NB*CAPB] (4MB)
    __hip_bfloat16* sxw         = (__hip_bfloat16*)d_ws;
    float*          rsq_out     = (float*)(sxw + (size_t)N_NODES * OUT_F);
    int*            bucket_cnt  = (int*)(rsq_out + N_NODES);
    int*            bucket_cnt2 = bucket_cnt + NB;
    int*            row_beg     = bucket_cnt2 + NB;
    int*            row_deg     = row_beg + N_NODES;
    unsigned*       pairs       = (unsigned*)(row_deg + N_NODES);
    unsigned char*  sbytes      = (unsigned char*)(pairs + (size_t)NB * CAPB);

    hipMemsetAsync(bucket_cnt, 0, 2 * (size_t)NB * sizeof(int), stream);

    partition_kernel<<<C_BLOCKS, 512, 0, stream>>>(src, dst, bucket_cnt,
                                                   bucket_cnt2, pairs, sbytes);

    mega_kernel<<<2 * NB + G_BLOCKS, 512, 0, stream>>>(
        pairs, bucket_cnt, sbytes, bucket_cnt2,
        row_beg, row_deg, rsq_out, in_feat, W, sxw);

    gather_kernel<<<N_NODES / 4, 256, 0, stream>>>(row_beg, row_deg, pairs,
                                                   (const uint4*)sxw, rsq_out,
                                                   b, out);
}

// Round 8
// 256.334 us; speedup vs baseline: 8.2578x; 1.0120x over previous
//
#include <hip/hip_runtime.h>
#include <hip/hip_bf16.h>

// GCN GraphConv (norm='both', mult-first): out = relu( D_in^-1/2 * A * D_out^-1/2 * (X W) + b )
// N=100000 nodes, E=3200000 edges, IN=128, OUT=64, fp32 in/out.
//
// R19 = R18 bodies, re-scheduled to overlap gemm with partition:
//  K1 pg: INTERLEAVED block ranges (even bid -> partition chunk bid/2,
//         odd bid -> gemm). Partition = R0-identical dual counting sort;
//         gemm = R0-identical loop, UNSCALED bf16 sxw. Opposite pipes
//         (LDS-atomic vs VALU), co-resident from t=0.
//  K2 cc: [0,NB) csr counting sort | [NB,2NB) count -> rsq_out  (R18 bodies).
//  K3 gather: R0 loop + per-edge rsq_out[s] scale (R17/R18-verified).
// Lessons enforced: no per-edge global atomics (R16: +90us), no float4-W gemm
// (R17: VGPR 108), no LDS f32 accumulation (R12/13: 1358us).

constexpr int N_NODES = 100000;
constexpr int N_EDGES = 3200000;
constexpr int IN_F    = 128;
constexpr int OUT_F   = 64;
constexpr int BUCKET_NODES = 256;
constexpr int NB   = (N_NODES + BUCKET_NODES - 1) / BUCKET_NODES;  // 391
constexpr int CAPB = 10240;          // bucket capacity; mean 8184, sd~90 -> 22 sigma
constexpr int C_CHUNK  = 4096;
constexpr int C_BLOCKS = (N_EDGES + C_CHUNK - 1) / C_CHUNK;        // 782 (last cn=1024, %4==0)
constexpr int G_TILE   = 32;         // gemm rows per block-iteration
constexpr int G_BLOCKS = 1024;
constexpr int G_GROUPS = N_NODES / G_TILE;                         // 3125
// K1 grid: 2*C_BLOCKS interleaved + (G_BLOCKS - C_BLOCKS) trailing gemm blocks
constexpr int PG_GRID  = 2 * C_BLOCKS + (G_BLOCKS - C_BLOCKS);     // 1806

// ---- Kernel 1 (pg): interleaved partition | gemm ----
__global__ __launch_bounds__(512) void pg_kernel(
        const int* __restrict__ src, const int* __restrict__ dst,
        int* __restrict__ bucket_cnt, int* __restrict__ bucket_cnt2,
        unsigned* __restrict__ pairs, unsigned char* __restrict__ sbytes,
        const float* __restrict__ x, const float* __restrict__ W,
        __hip_bfloat16* __restrict__ sxw) {
    alignas(16) __shared__ char smem[49408];   // partition 49408 | gemm 49152
    const int tid = threadIdx.x;
    const int bid = blockIdx.x;

    // interleaved mapping: even bid (below 2*C_BLOCKS) -> partition, else gemm
    bool is_part;
    int  idx;
    if (bid < 2 * C_BLOCKS) { is_part = (bid & 1) == 0; idx = bid >> 1; }
    else                    { is_part = false; idx = C_BLOCKS + (bid - 2 * C_BLOCKS); }

    if (is_part) {
        // ---------------- partition path (R0-identical body) ----------------
        int* l_cnt   = (int*)smem;                           // 1564 B each
        int* l_base  = l_cnt   + NB;
        int* l_pos   = l_base  + NB;
        int* g_base  = l_pos   + NB;
        int* l_cnt2  = g_base  + NB;
        int* l_base2 = l_cnt2  + NB;
        int* l_pos2  = l_base2 + NB;
        int* g_base2 = l_pos2  + NB;                         // ends @12512
        int* wsum_s  = g_base2 + NB;                         // 32 B @12512
        unsigned*       buf     = (unsigned*)(smem + 12544);       // 16384 B
        unsigned short* bkt_of  = (unsigned short*)(smem + 28928); // 8192 B
        unsigned char*  bbuf    = (unsigned char*)(smem + 37120);  // 4096 B
        unsigned short* bkt2_of = (unsigned short*)(smem + 41216); // 8192 B -> 49408

        const int lane = tid & 63;
        const int wid  = tid >> 6;                    // 0..7
        const long e0 = (long)idx * C_CHUNK;
        const int  cn = (int)min((long)C_CHUNK, (long)N_EDGES - e0);
        const int  cn4 = cn >> 2;                     // cn is always a multiple of 4

        for (int i = tid; i < NB; i += 512) { l_cnt[i] = 0; l_cnt2[i] = 0; }
        __syncthreads();

        unsigned r_pk[8];
        short    r_bk[8];
        const int4* d4p = (const int4*)(dst + e0);
        const int4* s4p = (const int4*)(src + e0);
        #pragma unroll
        for (int k = 0; k < 2; ++k) {
            int i4 = tid + k * 512;
            int rb = k * 4;
            if (i4 < cn4) {
                int4 d4 = d4p[i4];
                int4 s4 = s4p[i4];
                int dd[4] = {d4.x, d4.y, d4.z, d4.w};
                int ss[4] = {s4.x, s4.y, s4.z, s4.w};
                #pragma unroll
                for (int j = 0; j < 4; ++j) {
                    int bk = dd[j] >> 8;
                    r_bk[rb + j] = (short)bk;
                    r_pk[rb + j] = ((unsigned)(dd[j] & 255) << 17) | (unsigned)ss[j];
                    atomicAdd(&l_cnt[bk], 1);
                    atomicAdd(&l_cnt2[ss[j] >> 8], 1);
                }
            } else {
                #pragma unroll
                for (int j = 0; j < 4; ++j) r_bk[rb + j] = -1;
            }
        }
        __syncthreads();

        {   // scan 1: dst buckets
            int v = (tid < NB) ? l_cnt[tid] : 0;
            int inc = v;
            #pragma unroll
            for (int off = 1; off < 64; off <<= 1) {
                int t = __shfl_up(inc, off);
                if (lane >= off) inc += t;
            }
            if (lane == 63) wsum_s[wid] = inc;
            __syncthreads();
            int woff = 0;
            #pragma unroll
            for (int w = 0; w < 8; ++w) if (w < wid) woff += wsum_s[w];
            int excl = woff + inc - v;
            if (tid < NB) {
                l_base[tid] = excl;
                l_pos[tid]  = excl;
                g_base[tid] = v ? atomicAdd(&bucket_cnt[tid], v) : 0;
            }
        }
        __syncthreads();
        {   // scan 2: src buckets
            int v = (tid < NB) ? l_cnt2[tid] : 0;
            int inc = v;
            #pragma unroll
            for (int off = 1; off < 64; off <<= 1) {
                int t = __shfl_up(inc, off);
                if (lane >= off) inc += t;
            }
            if (lane == 63) wsum_s[wid] = inc;
            __syncthreads();
            int woff = 0;
            #pragma unroll
            for (int w = 0; w < 8; ++w) if (w < wid) woff += wsum_s[w];
            int excl = woff + inc - v;
            if (tid < NB) {
                l_base2[tid] = excl;
                l_pos2[tid]  = excl;
                g_base2[tid] = v ? atomicAdd(&bucket_cnt2[tid], v) : 0;
            }
        }
        __syncthreads();

        // scatter into LDS: both counting sorts
        #pragma unroll
        for (int k = 0; k < 8; ++k) {
            if (r_bk[k] >= 0) {
                unsigned pk = r_pk[k];
                int p = atomicAdd(&l_pos[(int)r_bk[k]], 1);
                buf[p] = pk;
                bkt_of[p] = (unsigned short)r_bk[k];
                int bk2 = (int)((pk >> 8) & 0x1FF);        // src >> 8
                int p2 = atomicAdd(&l_pos2[bk2], 1);
                bbuf[p2] = (unsigned char)(pk & 255);      // src & 255
                bkt2_of[p2] = (unsigned short)bk2;
            }
        }
        __syncthreads();

        // coalesced flushes
        for (int i = tid; i < cn; i += 512) {
            int bk = bkt_of[i];
            int gp = g_base[bk] + (i - l_base[bk]);
            if (gp < CAPB)                                 // 22-sigma safety
                pairs[(long)bk * CAPB + gp] = buf[i];
            int b2 = bkt2_of[i];
            int gp2 = g_base2[b2] + (i - l_base2[b2]);
            if (gp2 < CAPB)
                sbytes[(long)b2 * CAPB + gp2] = bbuf[i];
        }
    } else {
        // ---------------- gemm path (R0-identical loop, unscaled) ----------------
        float* Wl = (float*)smem;                  // 32768 B
        float* xl = (float*)(smem + 32768);        // 16384 B (32 rows x 128)
        for (int i = tid; i < IN_F * OUT_F; i += 512) Wl[i] = W[i];

        const int sub = tid >> 6;                  // 0..7 -> rows sub*4..sub*4+3
        const int col = tid & 63;

        for (int g = idx; g < G_GROUPS; g += G_BLOCKS) {
            __syncthreads();
            const float4* xg = (const float4*)(x + (long)g * G_TILE * IN_F);
            float4* xl4 = (float4*)xl;
            xl4[tid]       = xg[tid];
            xl4[tid + 512] = xg[tid + 512];
            __syncthreads();

            float a0 = 0.0f, a1 = 0.0f, a2 = 0.0f, a3 = 0.0f;
            const float* xr = xl + sub * 4 * IN_F;
            #pragma unroll
            for (int k4 = 0; k4 < IN_F / 4; ++k4) {
                float4 x0 = ((const float4*)xr)[k4];
                float4 x1 = ((const float4*)(xr + IN_F))[k4];
                float4 x2 = ((const float4*)(xr + 2 * IN_F))[k4];
                float4 x3 = ((const float4*)(xr + 3 * IN_F))[k4];
                float w0 = Wl[(k4 * 4 + 0) * OUT_F + col];
                float w1 = Wl[(k4 * 4 + 1) * OUT_F + col];
                float w2 = Wl[(k4 * 4 + 2) * OUT_F + col];
                float w3 = Wl[(k4 * 4 + 3) * OUT_F + col];
                a0 += x0.x * w0 + x0.y * w1 + x0.z * w2 + x0.w * w3;
                a1 += x1.x * w0 + x1.y * w1 + x1.z * w2 + x1.w * w3;
                a2 += x2.x * w0 + x2.y * w1 + x2.z * w2 + x2.w * w3;
                a3 += x3.x * w0 + x3.y * w1 + x3.z * w2 + x3.w * w3;
            }

            const int r0 = g * G_TILE + sub * 4;
            sxw[(long)(r0 + 0) * OUT_F + col] = __float2bfloat16(a0);
            sxw[(long)(r0 + 1) * OUT_F + col] = __float2bfloat16(a1);
            sxw[(long)(r0 + 2) * OUT_F + col] = __float2bfloat16(a2);
            sxw[(long)(r0 + 3) * OUT_F + col] = __float2bfloat16(a3);
        }
    }
}

// ---- Kernel 2 (cc): [0,NB) csr counting sort | [NB,2NB) count -> rsq ----
__global__ __launch_bounds__(512) void cc_kernel(
        unsigned* __restrict__ pairs, const int* __restrict__ bucket_cnt,
        const unsigned char* __restrict__ sbytes, const int* __restrict__ bucket_cnt2,
        int* __restrict__ row_beg, int* __restrict__ row_deg,
        float* __restrict__ rsq_out) {
    alignas(16) __shared__ char smem[43008];       // csr 43KB | count 1KB
    const int tid = threadIdx.x;

    if (blockIdx.x < NB) {
        // ---------------- csr path (R0-identical) ----------------
        unsigned* buf  = (unsigned*)smem;                    // 40960 B
        int*      hist = (int*)(smem + 40960);               // 1024 B
        int*      cur  = (int*)(smem + 40960 + 1024);        // 1024 B
        int*      wsum = (int*)(smem + 40960 + 2048);        // 16 B
        const int lane = tid & 63;
        const int wid  = tid >> 6;
        const int bk   = blockIdx.x;
        const long base = (long)bk * CAPB;
        const int cnt  = min(bucket_cnt[bk], CAPB);

        if (tid < 256) hist[tid] = 0;
        __syncthreads();

        const int c4 = cnt >> 2;
        const uint4* p4 = (const uint4*)(pairs + base);
        for (int i4 = tid; i4 < c4; i4 += 512) {
            uint4 e4 = p4[i4];
            ((uint4*)buf)[i4] = e4;                           // ds_write_b128
            atomicAdd(&hist[e4.x >> 17], 1);
            atomicAdd(&hist[e4.y >> 17], 1);
            atomicAdd(&hist[e4.z >> 17], 1);
            atomicAdd(&hist[e4.w >> 17], 1);
        }
        for (int i = (c4 << 2) + tid; i < cnt; i += 512) {
            unsigned e = pairs[base + i];
            buf[i] = e;
            atomicAdd(&hist[e >> 17], 1);
        }
        __syncthreads();

        int v = (tid < 256) ? hist[tid] : 0;
        int inc = v;
        #pragma unroll
        for (int off = 1; off < 64; off <<= 1) {
            int t = __shfl_up(inc, off);
            if (lane >= off) inc += t;
        }
        if (tid < 256 && lane == 63) wsum[wid] = inc;
        __syncthreads();
        if (tid < 256) {
            int woff = 0;
            #pragma unroll
            for (int w = 0; w < 4; ++w) if (w < wid) woff += wsum[w];
            int excl = woff + inc - v;
            cur[tid] = excl;
            const int node = bk * BUCKET_NODES + tid;
            if (node < N_NODES) {
                row_beg[node] = (int)(base + excl);
                row_deg[node] = v;
            }
        }
        __syncthreads();

        for (int i = tid; i < cnt; i += 512) {
            unsigned e = buf[i];
            int p = atomicAdd(&cur[e >> 17], 1);
            pairs[base + p] = e & 0x1FFFF;   // plain src, node-sorted
        }
    } else {
        // ---------------- count path: src-bucket histogram -> rsq_out ----------------
        int* hist = (int*)smem;                    // 1024 B
        const int bk = blockIdx.x - NB;
        if (tid < 256) hist[tid] = 0;
        __syncthreads();

        const int cnt = min(bucket_cnt2[bk], CAPB);
        const unsigned* sb4 = (const unsigned*)(sbytes + (long)bk * CAPB);
        const int n4 = cnt >> 2;
        for (int i = tid; i < n4; i += 512) {
            unsigned u = sb4[i];
            atomicAdd(&hist[u & 255], 1);
            atomicAdd(&hist[(u >> 8) & 255], 1);
            atomicAdd(&hist[(u >> 16) & 255], 1);
            atomicAdd(&hist[u >> 24], 1);
        }
        for (int i = (n4 << 2) + tid; i < cnt; i += 512)
            atomicAdd(&hist[sbytes[(long)bk * CAPB + i]], 1);
        __syncthreads();

        if (tid < 256) {
            const int node = bk * BUCKET_NODES + tid;
            if (node < N_NODES) {
                int d = hist[tid];
                rsq_out[node] = rsqrtf((float)(d < 1 ? 1 : d));
            }
        }
    }
}

// ---- Kernel 3: gather-sum per dst node + per-edge rsq_out scale ----
#define ACC8R(u, rs) {                                          \
    a0 = fmaf(__uint_as_float((u).x << 16),         (rs), a0);  \
    a1 = fmaf(__uint_as_float((u).x & 0xFFFF0000u), (rs), a1);  \
    a2 = fmaf(__uint_as_float((u).y << 16),         (rs), a2);  \
    a3 = fmaf(__uint_as_float((u).y & 0xFFFF0000u), (rs), a3);  \
    a4 = fmaf(__uint_as_float((u).z << 16),         (rs), a4);  \
    a5 = fmaf(__uint_as_float((u).z & 0xFFFF0000u), (rs), a5);  \
    a6 = fmaf(__uint_as_float((u).w << 16),         (rs), a6);  \
    a7 = fmaf(__uint_as_float((u).w & 0xFFFF0000u), (rs), a7);  \
}

__global__ __launch_bounds__(256) void gather_kernel(
        const int* __restrict__ row_beg, const int* __restrict__ row_deg,
        const unsigned* __restrict__ csr_src, const uint4* __restrict__ sxw4,
        const float* __restrict__ rsq_out,
        const float* __restrict__ b, float* __restrict__ out) {
    const int lane = threadIdx.x & 63;
    const int node = blockIdx.x * 4 + (threadIdx.x >> 6);

    const int eo = lane >> 3;     // edge slot 0..7
    const int c  = lane & 7;      // uint4 index within row (8 cols)

    const int beg = row_beg[node];
    const int deg = row_deg[node];
    const int end = beg + deg;

    float a0 = 0, a1 = 0, a2 = 0, a3 = 0, a4 = 0, a5 = 0, a6 = 0, a7 = 0;

    int j = beg;
    for (; j + 32 <= end; j += 32) {            // 4 row-loads in flight
        unsigned s0 = csr_src[j + eo];
        unsigned s1 = csr_src[j + 8 + eo];
        unsigned s2 = csr_src[j + 16 + eo];
        unsigned s3 = csr_src[j + 24 + eo];
        float r0 = rsq_out[s0], r1 = rsq_out[s1];
        float r2 = rsq_out[s2], r3 = rsq_out[s3];
        uint4 u0 = sxw4[(long)s0 * 8 + c];
        uint4 u1 = sxw4[(long)s1 * 8 + c];
        uint4 u2 = sxw4[(long)s2 * 8 + c];
        uint4 u3 = sxw4[(long)s3 * 8 + c];
        ACC8R(u0, r0) ACC8R(u1, r1) ACC8R(u2, r2) ACC8R(u3, r3)
    }
    for (; j + 8 <= end; j += 8) {
        unsigned s = csr_src[j + eo];
        float rs = rsq_out[s];
        uint4 u = sxw4[(long)s * 8 + c];
        ACC8R(u, rs)
    }
    if (j < end) {
        int e = j + eo;
        if (e < end) {
            unsigned s = csr_src[e];
            float rs = rsq_out[s];
            uint4 u = sxw4[(long)s * 8 + c];
            ACC8R(u, rs)
        }
    }

    #pragma unroll
    for (int off = 8; off < 64; off <<= 1) {
        a0 += __shfl_xor(a0, off);
        a1 += __shfl_xor(a1, off);
        a2 += __shfl_xor(a2, off);
        a3 += __shfl_xor(a3, off);
        a4 += __shfl_xor(a4, off);
        a5 += __shfl_xor(a5, off);
        a6 += __shfl_xor(a6, off);
        a7 += __shfl_xor(a7, off);
    }

    if (lane < 8) {
        float d = (float)(deg < 1 ? 1 : deg);
        float s = rsqrtf(d);
        float4 b0 = ((const float4*)b)[c * 2];
        float4 b1 = ((const float4*)b)[c * 2 + 1];
        float4 o0, o1;
        o0.x = a0 * s + b0.x; o0.x = o0.x > 0.0f ? o0.x : 0.0f;
        o0.y = a1 * s + b0.y; o0.y = o0.y > 0.0f ? o0.y : 0.0f;
        o0.z = a2 * s + b0.z; o0.z = o0.z > 0.0f ? o0.z : 0.0f;
        o0.w = a3 * s + b0.w; o0.w = o0.w > 0.0f ? o0.w : 0.0f;
        o1.x = a4 * s + b1.x; o1.x = o1.x > 0.0f ? o1.x : 0.0f;
        o1.y = a5 * s + b1.y; o1.y = o1.y > 0.0f ? o1.y : 0.0f;
        o1.z = a6 * s + b1.z; o1.z = o1.z > 0.0f ? o1.z : 0.0f;
        o1.w = a7 * s + b1.w; o1.w = o1.w > 0.0f ? o1.w : 0.0f;
        float4* orow = (float4*)(out + (long)node * OUT_F);
        orow[c * 2]     = o0;
        orow[c * 2 + 1] = o1;
    }
}

extern "C" void kernel_launch(void* const* d_in, const int* in_sizes, int n_in,
                              void* d_out, int out_size, void* d_ws, size_t ws_size,
                              hipStream_t stream) {
    const float* in_feat = (const float*)d_in[0];
    const int*   src     = (const int*)d_in[1];
    const int*   dst     = (const int*)d_in[2];
    const float* W       = (const float*)d_in[3];
    const float* b       = (const float*)d_in[4];
    float*       out     = (float*)d_out;

    // ws: sxw bf16 [N*64] (12.8MB) | rsq_out [N] | bucket_cnt [NB] | bucket_cnt2 [NB]
    //   | row_beg [N] | row_deg [N] | pairs [NB*CAPB u32] (16MB) | sbytes [NB*CAPB] (4MB)
    __hip_bfloat16* sxw         = (__hip_bfloat16*)d_ws;
    float*          rsq_out     = (float*)(sxw + (size_t)N_NODES * OUT_F);
    int*            bucket_cnt  = (int*)(rsq_out + N_NODES);
    int*            bucket_cnt2 = bucket_cnt + NB;
    int*            row_beg     = bucket_cnt2 + NB;
    int*            row_deg     = row_beg + N_NODES;
    unsigned*       pairs       = (unsigned*)(row_deg + N_NODES);
    unsigned char*  sbytes      = (unsigned char*)(pairs + (size_t)NB * CAPB);

    hipMemsetAsync(bucket_cnt, 0, 2 * (size_t)NB * sizeof(int), stream);

    pg_kernel<<<PG_GRID, 512, 0, stream>>>(src, dst, bucket_cnt, bucket_cnt2,
                                           pairs, sbytes, in_feat, W, sxw);

    cc_kernel<<<2 * NB, 512, 0, stream>>>(pairs, bucket_cnt, sbytes, bucket_cnt2,
                                          row_beg, row_deg, rsq_out);

    gather_kernel<<<N_NODES / 4, 256, 0, stream>>>(row_beg, row_deg, pairs,
                                                   (const uint4*)sxw, rsq_out,
                                                   b, out);
}

// Round 9
// 254.977 us; speedup vs baseline: 8.3018x; 1.0053x over previous
//
#include <hip/hip_runtime.h>
#include <hip/hip_bf16.h>

// GCN GraphConv (norm='both', mult-first): out = relu( D_in^-1/2 * A * D_out^-1/2 * (X W) + b )
// N=100000 nodes, E=3200000 edges, IN=128, OUT=64, fp32 in/out.
//
// R20 = R19 with cc's csr path made register-resident (R14-verified pattern):
//  K1 pg: INTERLEAVED partition | gemm (R19-verified, 85us, VGPR 40).
//  K2 cc: [0,NB) csr: pairs -> regs (ev[20]) -> hist atomics -> scan ->
//         scatter-from-regs (saves 2 LDS ops/edge + 40KB LDS -> more blocks/CU)
//         [NB,2NB) count -> rsq_out (R18 body).
//  K3 gather: R0 loop + per-edge rsq_out[s] scale (unchanged).
// Lessons enforced: no per-edge global atomics (R16), no float4-W gemm (R17),
// no LDS f32 accumulation (R12/13), occupancy > micro-opts (R17/R18).

constexpr int N_NODES = 100000;
constexpr int N_EDGES = 3200000;
constexpr int IN_F    = 128;
constexpr int OUT_F   = 64;
constexpr int BUCKET_NODES = 256;
constexpr int NB   = (N_NODES + BUCKET_NODES - 1) / BUCKET_NODES;  // 391
constexpr int CAPB = 10240;          // bucket capacity; mean 8184, sd~90 -> 22 sigma
constexpr int C_CHUNK  = 4096;
constexpr int C_BLOCKS = (N_EDGES + C_CHUNK - 1) / C_CHUNK;        // 782 (last cn=1024, %4==0)
constexpr int G_TILE   = 32;         // gemm rows per block-iteration
constexpr int G_BLOCKS = 1024;
constexpr int G_GROUPS = N_NODES / G_TILE;                         // 3125
constexpr int PG_GRID  = 2 * C_BLOCKS + (G_BLOCKS - C_BLOCKS);     // 1806

// ---- Kernel 1 (pg): interleaved partition | gemm (R19-identical) ----
__global__ __launch_bounds__(512) void pg_kernel(
        const int* __restrict__ src, const int* __restrict__ dst,
        int* __restrict__ bucket_cnt, int* __restrict__ bucket_cnt2,
        unsigned* __restrict__ pairs, unsigned char* __restrict__ sbytes,
        const float* __restrict__ x, const float* __restrict__ W,
        __hip_bfloat16* __restrict__ sxw) {
    alignas(16) __shared__ char smem[49408];   // partition 49408 | gemm 49152
    const int tid = threadIdx.x;
    const int bid = blockIdx.x;

    bool is_part;
    int  idx;
    if (bid < 2 * C_BLOCKS) { is_part = (bid & 1) == 0; idx = bid >> 1; }
    else                    { is_part = false; idx = C_BLOCKS + (bid - 2 * C_BLOCKS); }

    if (is_part) {
        // ---------------- partition path (R0-identical body) ----------------
        int* l_cnt   = (int*)smem;
        int* l_base  = l_cnt   + NB;
        int* l_pos   = l_base  + NB;
        int* g_base  = l_pos   + NB;
        int* l_cnt2  = g_base  + NB;
        int* l_base2 = l_cnt2  + NB;
        int* l_pos2  = l_base2 + NB;
        int* g_base2 = l_pos2  + NB;                         // ends @12512
        int* wsum_s  = g_base2 + NB;                         // 32 B @12512
        unsigned*       buf     = (unsigned*)(smem + 12544);       // 16384 B
        unsigned short* bkt_of  = (unsigned short*)(smem + 28928); // 8192 B
        unsigned char*  bbuf    = (unsigned char*)(smem + 37120);  // 4096 B
        unsigned short* bkt2_of = (unsigned short*)(smem + 41216); // 8192 B

        const int lane = tid & 63;
        const int wid  = tid >> 6;
        const long e0 = (long)idx * C_CHUNK;
        const int  cn = (int)min((long)C_CHUNK, (long)N_EDGES - e0);
        const int  cn4 = cn >> 2;

        for (int i = tid; i < NB; i += 512) { l_cnt[i] = 0; l_cnt2[i] = 0; }
        __syncthreads();

        unsigned r_pk[8];
        short    r_bk[8];
        const int4* d4p = (const int4*)(dst + e0);
        const int4* s4p = (const int4*)(src + e0);
        #pragma unroll
        for (int k = 0; k < 2; ++k) {
            int i4 = tid + k * 512;
            int rb = k * 4;
            if (i4 < cn4) {
                int4 d4 = d4p[i4];
                int4 s4 = s4p[i4];
                int dd[4] = {d4.x, d4.y, d4.z, d4.w};
                int ss[4] = {s4.x, s4.y, s4.z, s4.w};
                #pragma unroll
                for (int j = 0; j < 4; ++j) {
                    int bk = dd[j] >> 8;
                    r_bk[rb + j] = (short)bk;
                    r_pk[rb + j] = ((unsigned)(dd[j] & 255) << 17) | (unsigned)ss[j];
                    atomicAdd(&l_cnt[bk], 1);
                    atomicAdd(&l_cnt2[ss[j] >> 8], 1);
                }
            } else {
                #pragma unroll
                for (int j = 0; j < 4; ++j) r_bk[rb + j] = -1;
            }
        }
        __syncthreads();

        {   // scan 1: dst buckets
            int v = (tid < NB) ? l_cnt[tid] : 0;
            int inc = v;
            #pragma unroll
            for (int off = 1; off < 64; off <<= 1) {
                int t = __shfl_up(inc, off);
                if (lane >= off) inc += t;
            }
            if (lane == 63) wsum_s[wid] = inc;
            __syncthreads();
            int woff = 0;
            #pragma unroll
            for (int w = 0; w < 8; ++w) if (w < wid) woff += wsum_s[w];
            int excl = woff + inc - v;
            if (tid < NB) {
                l_base[tid] = excl;
                l_pos[tid]  = excl;
                g_base[tid] = v ? atomicAdd(&bucket_cnt[tid], v) : 0;
            }
        }
        __syncthreads();
        {   // scan 2: src buckets
            int v = (tid < NB) ? l_cnt2[tid] : 0;
            int inc = v;
            #pragma unroll
            for (int off = 1; off < 64; off <<= 1) {
                int t = __shfl_up(inc, off);
                if (lane >= off) inc += t;
            }
            if (lane == 63) wsum_s[wid] = inc;
            __syncthreads();
            int woff = 0;
            #pragma unroll
            for (int w = 0; w < 8; ++w) if (w < wid) woff += wsum_s[w];
            int excl = woff + inc - v;
            if (tid < NB) {
                l_base2[tid] = excl;
                l_pos2[tid]  = excl;
                g_base2[tid] = v ? atomicAdd(&bucket_cnt2[tid], v) : 0;
            }
        }
        __syncthreads();

        #pragma unroll
        for (int k = 0; k < 8; ++k) {
            if (r_bk[k] >= 0) {
                unsigned pk = r_pk[k];
                int p = atomicAdd(&l_pos[(int)r_bk[k]], 1);
                buf[p] = pk;
                bkt_of[p] = (unsigned short)r_bk[k];
                int bk2 = (int)((pk >> 8) & 0x1FF);
                int p2 = atomicAdd(&l_pos2[bk2], 1);
                bbuf[p2] = (unsigned char)(pk & 255);
                bkt2_of[p2] = (unsigned short)bk2;
            }
        }
        __syncthreads();

        for (int i = tid; i < cn; i += 512) {
            int bk = bkt_of[i];
            int gp = g_base[bk] + (i - l_base[bk]);
            if (gp < CAPB)
                pairs[(long)bk * CAPB + gp] = buf[i];
            int b2 = bkt2_of[i];
            int gp2 = g_base2[b2] + (i - l_base2[b2]);
            if (gp2 < CAPB)
                sbytes[(long)b2 * CAPB + gp2] = bbuf[i];
        }
    } else {
        // ---------------- gemm path (R0-identical loop, unscaled) ----------------
        float* Wl = (float*)smem;                  // 32768 B
        float* xl = (float*)(smem + 32768);        // 16384 B
        for (int i = tid; i < IN_F * OUT_F; i += 512) Wl[i] = W[i];

        const int sub = tid >> 6;
        const int col = tid & 63;

        for (int g = idx; g < G_GROUPS; g += G_BLOCKS) {
            __syncthreads();
            const float4* xg = (const float4*)(x + (long)g * G_TILE * IN_F);
            float4* xl4 = (float4*)xl;
            xl4[tid]       = xg[tid];
            xl4[tid + 512] = xg[tid + 512];
            __syncthreads();

            float a0 = 0.0f, a1 = 0.0f, a2 = 0.0f, a3 = 0.0f;
            const float* xr = xl + sub * 4 * IN_F;
            #pragma unroll
            for (int k4 = 0; k4 < IN_F / 4; ++k4) {
                float4 x0 = ((const float4*)xr)[k4];
                float4 x1 = ((const float4*)(xr + IN_F))[k4];
                float4 x2 = ((const float4*)(xr + 2 * IN_F))[k4];
                float4 x3 = ((const float4*)(xr + 3 * IN_F))[k4];
                float w0 = Wl[(k4 * 4 + 0) * OUT_F + col];
                float w1 = Wl[(k4 * 4 + 1) * OUT_F + col];
                float w2 = Wl[(k4 * 4 + 2) * OUT_F + col];
                float w3 = Wl[(k4 * 4 + 3) * OUT_F + col];
                a0 += x0.x * w0 + x0.y * w1 + x0.z * w2 + x0.w * w3;
                a1 += x1.x * w0 + x1.y * w1 + x1.z * w2 + x1.w * w3;
                a2 += x2.x * w0 + x2.y * w1 + x2.z * w2 + x2.w * w3;
                a3 += x3.x * w0 + x3.y * w1 + x3.z * w2 + x3.w * w3;
            }

            const int r0 = g * G_TILE + sub * 4;
            sxw[(long)(r0 + 0) * OUT_F + col] = __float2bfloat16(a0);
            sxw[(long)(r0 + 1) * OUT_F + col] = __float2bfloat16(a1);
            sxw[(long)(r0 + 2) * OUT_F + col] = __float2bfloat16(a2);
            sxw[(long)(r0 + 3) * OUT_F + col] = __float2bfloat16(a3);
        }
    }
}

// ---- Kernel 2 (cc): [0,NB) csr (register-resident) | [NB,2NB) count -> rsq ----
__global__ __launch_bounds__(512) void cc_kernel(
        unsigned* __restrict__ pairs, const int* __restrict__ bucket_cnt,
        const unsigned char* __restrict__ sbytes, const int* __restrict__ bucket_cnt2,
        int* __restrict__ row_beg, int* __restrict__ row_deg,
        float* __restrict__ rsq_out) {
    alignas(16) __shared__ char smem[4096];        // hist 1KB | cur 1KB | wsum
    const int tid = threadIdx.x;

    if (blockIdx.x < NB) {
        // ---------------- csr path: regs + hist + scan + scatter-from-regs ----------------
        int* hist = (int*)smem;                    // 1024 B
        int* cur  = hist + 256;                    // 1024 B
        int* wsum = cur + 256;                     // 16 B
        const int lane = tid & 63;
        const int wid  = tid >> 6;
        const int bk   = blockIdx.x;
        const long base = (long)bk * CAPB;
        const int cnt  = min(bucket_cnt[bk], CAPB);
        const int n4   = cnt >> 2;                 // <= 2560
        const uint4* p4 = (const uint4*)(pairs + base);

        if (tid < 256) hist[tid] = 0;
        __syncthreads();

        // load up to 20 edges/thread into registers, histogram dl (1 atomic/edge)
        unsigned ev[20];
        #pragma unroll
        for (int k = 0; k < 5; ++k) {
            const int i4 = tid + k * 512;
            if (i4 < n4) {
                uint4 q = p4[i4];
                ev[k * 4 + 0] = q.x; ev[k * 4 + 1] = q.y;
                ev[k * 4 + 2] = q.z; ev[k * 4 + 3] = q.w;
                atomicAdd(&hist[q.x >> 17], 1);
                atomicAdd(&hist[q.y >> 17], 1);
                atomicAdd(&hist[q.z >> 17], 1);
                atomicAdd(&hist[q.w >> 17], 1);
            } else {
                ev[k * 4 + 0] = 0xFFFFFFFFu; ev[k * 4 + 1] = 0xFFFFFFFFu;
                ev[k * 4 + 2] = 0xFFFFFFFFu; ev[k * 4 + 3] = 0xFFFFFFFFu;
            }
        }
        unsigned et = 0xFFFFFFFFu;                 // tail (cnt & 3 edges)
        if (tid < (cnt & 3)) {
            et = pairs[base + (n4 << 2) + tid];
            atomicAdd(&hist[et >> 17], 1);
        }
        __syncthreads();

        // exclusive scan of 256 bins (4 waves of first 256 threads)
        int v = (tid < 256) ? hist[tid] : 0;
        int inc = v;
        #pragma unroll
        for (int off = 1; off < 64; off <<= 1) {
            int t = __shfl_up(inc, off);
            if (lane >= off) inc += t;
        }
        if (tid < 256 && lane == 63) wsum[wid] = inc;
        __syncthreads();
        if (tid < 256) {
            int woff = 0;
            #pragma unroll
            for (int w = 0; w < 4; ++w) if (w < wid) woff += wsum[w];
            int excl = woff + inc - v;
            cur[tid] = excl;
            const int node = bk * BUCKET_NODES + tid;
            if (node < N_NODES) {
                row_beg[node] = (int)(base + excl);
                row_deg[node] = v;
            }
        }
        __syncthreads();

        // scatter src from regs to node-sorted positions (all reads already done)
        #pragma unroll
        for (int k = 0; k < 20; ++k) {
            if (ev[k] != 0xFFFFFFFFu) {
                int p = atomicAdd(&cur[ev[k] >> 17], 1);
                pairs[base + p] = ev[k] & 0x1FFFF;
            }
        }
        if (et != 0xFFFFFFFFu) {
            int p = atomicAdd(&cur[et >> 17], 1);
            pairs[base + p] = et & 0x1FFFF;
        }
    } else {
        // ---------------- count path: src-bucket histogram -> rsq_out ----------------
        int* hist = (int*)smem;                    // 1024 B
        const int bk = blockIdx.x - NB;
        if (tid < 256) hist[tid] = 0;
        __syncthreads();

        const int cnt = min(bucket_cnt2[bk], CAPB);
        const unsigned* sb4 = (const unsigned*)(sbytes + (long)bk * CAPB);
        const int n4 = cnt >> 2;
        for (int i = tid; i < n4; i += 512) {
            unsigned u = sb4[i];
            atomicAdd(&hist[u & 255], 1);
            atomicAdd(&hist[(u >> 8) & 255], 1);
            atomicAdd(&hist[(u >> 16) & 255], 1);
            atomicAdd(&hist[u >> 24], 1);
        }
        for (int i = (n4 << 2) + tid; i < cnt; i += 512)
            atomicAdd(&hist[sbytes[(long)bk * CAPB + i]], 1);
        __syncthreads();

        if (tid < 256) {
            const int node = bk * BUCKET_NODES + tid;
            if (node < N_NODES) {
                int d = hist[tid];
                rsq_out[node] = rsqrtf((float)(d < 1 ? 1 : d));
            }
        }
    }
}

// ---- Kernel 3: gather-sum per dst node + per-edge rsq_out scale ----
#define ACC8R(u, rs) {                                          \
    a0 = fmaf(__uint_as_float((u).x << 16),         (rs), a0);  \
    a1 = fmaf(__uint_as_float((u).x & 0xFFFF0000u), (rs), a1);  \
    a2 = fmaf(__uint_as_float((u).y << 16),         (rs), a2);  \
    a3 = fmaf(__uint_as_float((u).y & 0xFFFF0000u), (rs), a3);  \
    a4 = fmaf(__uint_as_float((u).z << 16),         (rs), a4);  \
    a5 = fmaf(__uint_as_float((u).z & 0xFFFF0000u), (rs), a5);  \
    a6 = fmaf(__uint_as_float((u).w << 16),         (rs), a6);  \
    a7 = fmaf(__uint_as_float((u).w & 0xFFFF0000u), (rs), a7);  \
}

__global__ __launch_bounds__(256) void gather_kernel(
        const int* __restrict__ row_beg, const int* __restrict__ row_deg,
        const unsigned* __restrict__ csr_src, const uint4* __restrict__ sxw4,
        const float* __restrict__ rsq_out,
        const float* __restrict__ b, float* __restrict__ out) {
    const int lane = threadIdx.x & 63;
    const int node = blockIdx.x * 4 + (threadIdx.x >> 6);

    const int eo = lane >> 3;     // edge slot 0..7
    const int c  = lane & 7;      // uint4 index within row (8 cols)

    const int beg = row_beg[node];
    const int deg = row_deg[node];
    const int end = beg + deg;

    float a0 = 0, a1 = 0, a2 = 0, a3 = 0, a4 = 0, a5 = 0, a6 = 0, a7 = 0;

    int j = beg;
    for (; j + 32 <= end; j += 32) {            // 4 row-loads in flight
        unsigned s0 = csr_src[j + eo];
        unsigned s1 = csr_src[j + 8 + eo];
        unsigned s2 = csr_src[j + 16 + eo];
        unsigned s3 = csr_src[j + 24 + eo];
        float r0 = rsq_out[s0], r1 = rsq_out[s1];
        float r2 = rsq_out[s2], r3 = rsq_out[s3];
        uint4 u0 = sxw4[(long)s0 * 8 + c];
        uint4 u1 = sxw4[(long)s1 * 8 + c];
        uint4 u2 = sxw4[(long)s2 * 8 + c];
        uint4 u3 = sxw4[(long)s3 * 8 + c];
        ACC8R(u0, r0) ACC8R(u1, r1) ACC8R(u2, r2) ACC8R(u3, r3)
    }
    for (; j + 8 <= end; j += 8) {
        unsigned s = csr_src[j + eo];
        float rs = rsq_out[s];
        uint4 u = sxw4[(long)s * 8 + c];
        ACC8R(u, rs)
    }
    if (j < end) {
        int e = j + eo;
        if (e < end) {
            unsigned s = csr_src[e];
            float rs = rsq_out[s];
            uint4 u = sxw4[(long)s * 8 + c];
            ACC8R(u, rs)
        }
    }

    #pragma unroll
    for (int off = 8; off < 64; off <<= 1) {
        a0 += __shfl_xor(a0, off);
        a1 += __shfl_xor(a1, off);
        a2 += __shfl_xor(a2, off);
        a3 += __shfl_xor(a3, off);
        a4 += __shfl_xor(a4, off);
        a5 += __shfl_xor(a5, off);
        a6 += __shfl_xor(a6, off);
        a7 += __shfl_xor(a7, off);
    }

    if (lane < 8) {
        float d = (float)(deg < 1 ? 1 : deg);
        float s = rsqrtf(d);
        float4 b0 = ((const float4*)b)[c * 2];
        float4 b1 = ((const float4*)b)[c * 2 + 1];
        float4 o0, o1;
        o0.x = a0 * s + b0.x; o0.x = o0.x > 0.0f ? o0.x : 0.0f;
        o0.y = a1 * s + b0.y; o0.y = o0.y > 0.0f ? o0.y : 0.0f;
        o0.z = a2 * s + b0.z; o0.z = o0.z > 0.0f ? o0.z : 0.0f;
        o0.w = a3 * s + b0.w; o0.w = o0.w > 0.0f ? o0.w : 0.0f;
        o1.x = a4 * s + b1.x; o1.x = o1.x > 0.0f ? o1.x : 0.0f;
        o1.y = a5 * s + b1.y; o1.y = o1.y > 0.0f ? o1.y : 0.0f;
        o1.z = a6 * s + b1.z; o1.z = o1.z > 0.0f ? o1.z : 0.0f;
        o1.w = a7 * s + b1.w; o1.w = o1.w > 0.0f ? o1.w : 0.0f;
        float4* orow = (float4*)(out + (long)node * OUT_F);
        orow[c * 2]     = o0;
        orow[c * 2 + 1] = o1;
    }
}

extern "C" void kernel_launch(void* const* d_in, const int* in_sizes, int n_in,
                              void* d_out, int out_size, void* d_ws, size_t ws_size,
                              hipStream_t stream) {
    const float* in_feat = (const float*)d_in[0];
    const int*   src     = (const int*)d_in[1];
    const int*   dst     = (const int*)d_in[2];
    const float* W       = (const float*)d_in[3];
    const float* b       = (const float*)d_in[4];
    float*       out     = (float*)d_out;

    // ws: sxw bf16 [N*64] (12.8MB) | rsq_out [N] | bucket_cnt [NB] | bucket_cnt2 [NB]
    //   | row_beg [N] | row_deg [N] | pairs [NB*CAPB u32] (16MB) | sbytes [NB*CAPB] (4MB)
    __hip_bfloat16* sxw         = (__hip_bfloat16*)d_ws;
    float*          rsq_out     = (float*)(sxw + (size_t)N_NODES * OUT_F);
    int*            bucket_cnt  = (int*)(rsq_out + N_NODES);
    int*            bucket_cnt2 = bucket_cnt + NB;
    int*            row_beg     = bucket_cnt2 + NB;
    int*            row_deg     = row_beg + N_NODES;
    unsigned*       pairs       = (unsigned*)(row_deg + N_NODES);
    unsigned char*  sbytes      = (unsigned char*)(pairs + (size_t)NB * CAPB);

    hipMemsetAsync(bucket_cnt, 0, 2 * (size_t)NB * sizeof(int), stream);

    pg_kernel<<<PG_GRID, 512, 0, stream>>>(src, dst, bucket_cnt, bucket_cnt2,
                                           pairs, sbytes, in_feat, W, sxw);

    cc_kernel<<<2 * NB, 512, 0, stream>>>(pairs, bucket_cnt, sbytes, bucket_cnt2,
                                          row_beg, row_deg, rsq_out);

    gather_kernel<<<N_NODES / 4, 256, 0, stream>>>(row_beg, row_deg, pairs,
                                                   (const uint4*)sxw, rsq_out,
                                                   b, out);
}